// Round 4
// baseline (844.825 us; speedup 1.0000x reference)
//
#include <hip/hip_runtime.h>
#include <stdint.h>

typedef __attribute__((ext_vector_type(8))) short short8;
typedef __attribute__((ext_vector_type(4))) float f32x4;

#define TT 512
#define LSTR 136   // sZ/sY row stride in ushorts: 272B -> spread banks
#define XS 516     // sX row stride in floats

static __device__ __forceinline__ uint32_t f2bf_u(float f){
  union { float f; uint32_t u; } v; v.f = f;
  return (v.u + 0x7fffu + ((v.u >> 16) & 1u)) >> 16;
}
static __device__ __forceinline__ short8 w8f32(const float* p){
  float4 a = *(const float4*)p;
  float4 b = *(const float4*)(p + 4);
  short8 r;
  r[0] = (short)f2bf_u(a.x); r[1] = (short)f2bf_u(a.y);
  r[2] = (short)f2bf_u(a.z); r[3] = (short)f2bf_u(a.w);
  r[4] = (short)f2bf_u(b.x); r[5] = (short)f2bf_u(b.y);
  r[6] = (short)f2bf_u(b.z); r[7] = (short)f2bf_u(b.w);
  return r;
}
// 4 Whh columns, each duplicated into an adjacent bf16 pair: multiplies the
// interleaved (hi,lo) k-layout of sZ.
static __device__ __forceinline__ short8 w8dup(const float* p){
  float4 a = *(const float4*)p;
  short w0 = (short)f2bf_u(a.x), w1 = (short)f2bf_u(a.y);
  short w2 = (short)f2bf_u(a.z), w3 = (short)f2bf_u(a.w);
  short8 r;
  r[0] = w0; r[1] = w0; r[2] = w1; r[3] = w1;
  r[4] = w2; r[5] = w2; r[6] = w3; r[7] = w3;
  return r;
}
// sigmoid via exp2+rcp: inf-safe (exp2->inf => rcp->0).
static __device__ __forceinline__ float sigx(float x){
  float e = __builtin_amdgcn_exp2f(-1.442695040888963f * x);
  return __builtin_amdgcn_rcpf(1.f + e);
}
// tanh(x) = 2*sigmoid(2x)-1: no clamp needed.
static __device__ __forceinline__ float tanhx(float x){
  float e = __builtin_amdgcn_exp2f(-2.885390081777927f * x);
  return fmaf(__builtin_amdgcn_rcpf(1.f + e), 2.f, -1.f);
}
// LDS-only barrier: waits ds ops, leaves global loads/stores in flight.
static __device__ __forceinline__ void lds_barrier(){
  asm volatile("s_waitcnt lgkmcnt(0)" ::: "memory");
  __builtin_amdgcn_s_barrier();
}
#define MF(A,B,C) __builtin_amdgcn_mfma_f32_16x16x32_bf16((A),(B),(C),0,0,0)

// 4-chain redistributed nonlinearity. N-cols are 4-fold batch-dup
// (col = batch + 4*copy); lane selects its chain by copy = m16>>2 via
// v_cndmask (no cross-lane ops). Each lane handles ONE (batch,unit) pair.
// h written as packed (hi | lo<<16) word to all 4 dup rows.
#define NONLIN_WRITE4(C0_, C1_, C2_, C3_, P1) do { \
    f32x4 ga_, gb_, g_; \
    ga_[0] = selA ? (C1_)[0] : (C0_)[0]; \
    ga_[1] = selA ? (C1_)[1] : (C0_)[1]; \
    ga_[2] = selA ? (C1_)[2] : (C0_)[2]; \
    ga_[3] = selA ? (C1_)[3] : (C0_)[3]; \
    gb_[0] = selA ? (C3_)[0] : (C2_)[0]; \
    gb_[1] = selA ? (C3_)[1] : (C2_)[1]; \
    gb_[2] = selA ? (C3_)[2] : (C2_)[2]; \
    gb_[3] = selA ? (C3_)[3] : (C2_)[3]; \
    g_[0] = selB ? gb_[0] : ga_[0]; \
    g_[1] = selB ? gb_[1] : ga_[1]; \
    g_[2] = selB ? gb_[2] : ga_[2]; \
    g_[3] = selB ? gb_[3] : ga_[3]; \
    float ii_ = sigx(g_[0]), ff_ = sigx(g_[1]), gg_ = tanhx(g_[2]), oo_ = sigx(g_[3]); \
    c = fmaf(ff_, c, ii_ * gg_); \
    h = oo_ * tanhx(c); \
    { union { float f; uint32_t u; } hv_; hv_.f = h; \
      uint32_t r_ = hv_.u + 0x7fffu + ((hv_.u >> 16) & 1u); \
      union { uint32_t u; float f; } hi_; hi_.u = r_ & 0xffff0000u; \
      union { float f; uint32_t u; } lv_; lv_.f = h - hi_.f; \
      uint32_t pk_ = (r_ >> 16) | (lv_.u & 0xffff0000u); \
      *(uint32_t*)&sZ[P1][bcol][2 * unit]      = pk_; \
      *(uint32_t*)&sZ[P1][bcol + 4][2 * unit]  = pk_; \
      *(uint32_t*)&sZ[P1][bcol + 8][2 * unit]  = pk_; \
      *(uint32_t*)&sZ[P1][bcol + 12][2 * unit] = pk_; } \
  } while(0)

// ==================== Layer 0 ====================
// 256 thr / 4 waves / 4 batches; wave w owns rowtiles 4w..4w+3 (4 MFMA chains).
// Grid 512 -> 2 independent blocks per CU (stall overlap).
__global__ __launch_bounds__(256, 2) void lstm_l0(
    const float* __restrict__ x,   // [B][3][T]
    const float* __restrict__ Wih_f, const float* __restrict__ Whh_f,
    const float* __restrict__ bih_f, const float* __restrict__ bhh_f,
    const float* __restrict__ Wih_b, const float* __restrict__ Whh_b,
    const float* __restrict__ bih_b, const float* __restrict__ bhh_b,
    unsigned short* __restrict__ y0)  // [B][T][128] bf16
{
  const int tid = threadIdx.x;
  const int wv = tid >> 6, lane = tid & 63;
  const int quad = lane >> 4, m16 = lane & 15;
  const int dir = blockIdx.y;
  const int bbase = blockIdx.x * 4;
  const float* Wih = dir ? Wih_b : Wih_f;
  const float* Whh = dir ? Whh_b : Whh_f;
  const float* bih = dir ? bih_b : bih_f;
  const float* bhh = dir ? bhh_b : bhh_f;

  __shared__ __align__(16) unsigned short sZ[2][16][LSTR];
  __shared__ __align__(16) float sX[12 * XS];

  // A-frags: tile-row rho -> gate (rho&3), unit-offset (rho>>2).
  short8 aH[4][4], aX[4];
  f32x4 biasv[4];
  const int gm = (m16 & 3) * 64 + (m16 >> 2);
  #pragma unroll
  for (int k = 0; k < 4; k++){
    const int rt = 4 * wv + k;
    const int g = gm + 4 * rt;
    #pragma unroll
    for (int m = 0; m < 4; m++) aH[k][m] = w8dup(Whh + g * 64 + m * 16 + quad * 4);
    short8 ax = {0,0,0,0,0,0,0,0};
    if (quad == 0){
      ax[0] = (short)f2bf_u(Wih[g * 3 + 0]);
      ax[1] = (short)f2bf_u(Wih[g * 3 + 1]);
      ax[2] = (short)f2bf_u(Wih[g * 3 + 2]);
    }
    aX[k] = ax;
    const int gu = 4 * rt + quad;   // C reg r -> gate row r*64 + gu
    #pragma unroll
    for (int r = 0; r < 4; r++) biasv[k][r] = bih[r * 64 + gu] + bhh[r * 64 + gu];
  }

  for (int idx = tid; idx < 2 * 16 * LSTR; idx += 256)
    ((unsigned short*)sZ)[idx] = 0;
  for (int i4 = tid; i4 < 1536; i4 += 256){
    const int row = i4 >> 7, t4 = (i4 & 127) * 4;
    *(float4*)&sX[row * XS + t4] = *(const float4*)(x + (size_t)bbase * 1536 + row * 512 + t4);
  }
  __syncthreads();

  const int bcol = m16 & 3;
  const int xrow = 3 * bcol;
  const bool selA = (m16 & 4) != 0;
  const bool selB = (m16 & 8) != 0;
  const int unit = 16 * wv + 4 * (m16 >> 2) + quad;
  float c = 0.f, h = 0.f;
  const f32x4 z4 = {0.f, 0.f, 0.f, 0.f};

#define L0STEP(S, P) do { \
    const int t_ = dir ? (TT - 1 - (S)) : (S); \
    short8 b0 = *(const short8*)&sZ[P][m16][     quad * 8]; \
    short8 b1 = *(const short8*)&sZ[P][m16][32 + quad * 8]; \
    short8 b2 = *(const short8*)&sZ[P][m16][64 + quad * 8]; \
    short8 b3 = *(const short8*)&sZ[P][m16][96 + quad * 8]; \
    short8 bx = {0,0,0,0,0,0,0,0}; \
    if (quad == 0){ \
      bx[0] = (short)f2bf_u(sX[xrow * XS + t_]); \
      bx[1] = (short)f2bf_u(sX[(xrow + 1) * XS + t_]); \
      bx[2] = (short)f2bf_u(sX[(xrow + 2) * XS + t_]); \
    } \
    if (wv == 3 && lane < 32 && (S) > 0){ \
      const int tprev = dir ? (TT - (S)) : ((S) - 1); \
      const int br_ = lane >> 3, cc_ = lane & 7; \
      const uint32_t* wp_ = (const uint32_t*)&sZ[P][br_][16 * cc_]; \
      uint4 wa_ = *(const uint4*)(wp_); \
      uint4 wb_ = *(const uint4*)(wp_ + 4); \
      uint4 o_; \
      o_.x = (wa_.x & 0xffffu) | (wa_.y << 16); \
      o_.y = (wa_.z & 0xffffu) | (wa_.w << 16); \
      o_.z = (wb_.x & 0xffffu) | (wb_.y << 16); \
      o_.w = (wb_.z & 0xffffu) | (wb_.w << 16); \
      *(uint4*)(y0 + ((size_t)(bbase + br_) * TT + tprev) * 128 + dir * 64 + cc_ * 8) = o_; \
    } \
    f32x4 A0 = MF(aH[0][0], b0, biasv[0]); \
    f32x4 A1 = MF(aH[1][0], b0, biasv[1]); \
    f32x4 A2 = MF(aH[2][0], b0, biasv[2]); \
    f32x4 A3 = MF(aH[3][0], b0, biasv[3]); \
    A0 = MF(aH[0][1], b1, A0);  A1 = MF(aH[1][1], b1, A1); \
    A2 = MF(aH[2][1], b1, A2);  A3 = MF(aH[3][1], b1, A3); \
    f32x4 B0 = MF(aX[0], bx, z4); \
    f32x4 B1 = MF(aX[1], bx, z4); \
    f32x4 B2 = MF(aX[2], bx, z4); \
    f32x4 B3 = MF(aX[3], bx, z4); \
    B0 = MF(aH[0][2], b2, B0);  B1 = MF(aH[1][2], b2, B1); \
    B2 = MF(aH[2][2], b2, B2);  B3 = MF(aH[3][2], b2, B3); \
    B0 = MF(aH[0][3], b3, B0);  B1 = MF(aH[1][3], b3, B1); \
    B2 = MF(aH[2][3], b3, B2);  B3 = MF(aH[3][3], b3, B3); \
    f32x4 C0 = A0 + B0, C1 = A1 + B1, C2 = A2 + B2, C3 = A3 + B3; \
    NONLIN_WRITE4(C0, C1, C2, C3, (1 - (P))); \
    lds_barrier(); \
  } while(0)

  for (int s = 0; s < TT; s += 2){
    L0STEP(s, 0);
    L0STEP(s + 1, 1);
  }
#undef L0STEP

  // final timestep's h (last write went to sZ[0])
  if (wv == 3 && lane < 32){
    const int tl = dir ? 0 : (TT - 1);
    const int br = lane >> 3, cc = lane & 7;
    const uint32_t* wp = (const uint32_t*)&sZ[0][br][16 * cc];
    uint4 wa = *(const uint4*)(wp);
    uint4 wb = *(const uint4*)(wp + 4);
    uint4 o;
    o.x = (wa.x & 0xffffu) | (wa.y << 16);
    o.y = (wa.z & 0xffffu) | (wa.w << 16);
    o.z = (wb.x & 0xffffu) | (wb.y << 16);
    o.w = (wb.z & 0xffffu) | (wb.w << 16);
    *(uint4*)(y0 + ((size_t)(bbase + br) * TT + tl) * 128 + dir * 64 + cc * 8) = o;
  }
}

// ==================== Layer 1 ====================
// 256 thr / 4 waves / 4 batches, 4 chains/wave; y0 via 4-slot LDS ring
// staged by wave 0. Grid 512 -> 2 blocks/CU.
__global__ __launch_bounds__(256, 2) void lstm_l1(
    const unsigned short* __restrict__ y0,  // [B][T][128] bf16
    const float* __restrict__ Wih_f, const float* __restrict__ Whh_f,
    const float* __restrict__ bih_f, const float* __restrict__ bhh_f,
    const float* __restrict__ Wih_b, const float* __restrict__ Whh_b,
    const float* __restrict__ bih_b, const float* __restrict__ bhh_b,
    float* __restrict__ hT)                 // [B][128] fp32
{
  const int tid = threadIdx.x;
  const int wv = tid >> 6, lane = tid & 63;
  const int quad = lane >> 4, m16 = lane & 15;
  const int dir = blockIdx.y;
  const int bbase = blockIdx.x * 4;
  const float* Wih = dir ? Wih_b : Wih_f;
  const float* Whh = dir ? Whh_b : Whh_f;
  const float* bih = dir ? bih_b : bih_f;
  const float* bhh = dir ? bhh_b : bhh_f;

  __shared__ __align__(16) unsigned short sZ[2][16][LSTR];
  __shared__ __align__(16) unsigned short sY[4][4][LSTR];   // 4-slot y0 ring

  short8 aY[4][4], aH[4][4];
  f32x4 biasv[4];
  const int gm = (m16 & 3) * 64 + (m16 >> 2);
  #pragma unroll
  for (int k = 0; k < 4; k++){
    const int rt = 4 * wv + k;
    const int g = gm + 4 * rt;
    #pragma unroll
    for (int kt = 0; kt < 4; kt++) aY[k][kt] = w8f32(Wih + g * 128 + kt * 32 + quad * 8);
    #pragma unroll
    for (int m = 0; m < 4; m++) aH[k][m] = w8dup(Whh + g * 64 + m * 16 + quad * 4);
    const int gu = 4 * rt + quad;
    #pragma unroll
    for (int r = 0; r < 4; r++) biasv[k][r] = bih[r * 64 + gu] + bhh[r * 64 + gu];
  }

  for (int idx = tid; idx < 2 * 16 * LSTR; idx += 256)
    ((unsigned short*)sZ)[idx] = 0;

  // staging (wave 0): row = lane>>4 (batch 0..3), chunk = lane&15 (16B)
  const int srow = lane >> 4, schunk = lane & 15;
  const size_t sgbase = (size_t)(bbase + srow) * TT * 128 + schunk * 8;
  float4 hA = make_float4(0.f,0.f,0.f,0.f), hB = make_float4(0.f,0.f,0.f,0.f);
  if (wv == 0){
    const int t0 = dir ? (TT-1) : 0, t1 = dir ? (TT-2) : 1, t2 = dir ? (TT-3) : 2;
    const int t3 = dir ? (TT-4) : 3, t4 = dir ? (TT-5) : 4;
    float4 v0 = *(const float4*)(y0 + sgbase + (size_t)t0 * 128);
    float4 v1 = *(const float4*)(y0 + sgbase + (size_t)t1 * 128);
    float4 v2 = *(const float4*)(y0 + sgbase + (size_t)t2 * 128);
    hA = *(const float4*)(y0 + sgbase + (size_t)t3 * 128);
    hB = *(const float4*)(y0 + sgbase + (size_t)t4 * 128);
    *(float4*)&sY[0][srow][schunk * 8] = v0;
    *(float4*)&sY[1][srow][schunk * 8] = v1;
    *(float4*)&sY[2][srow][schunk * 8] = v2;
  }
  __syncthreads();

  const int bcol = m16 & 3;
  const bool selA = (m16 & 4) != 0;
  const bool selB = (m16 & 8) != 0;
  const int unit = 16 * wv + 4 * (m16 >> 2) + quad;
  float c = 0.f, h = 0.f;
  const f32x4 z4 = {0.f, 0.f, 0.f, 0.f};

#define L1STEP(S, HOLD) do { \
    const int p = (S) & 1, p1 = p ^ 1, slot = (S) & 3; \
    if (wv == 0){ \
      *(float4*)&sY[((S) + 3) & 3][srow][schunk * 8] = HOLD; \
      int sg = (S) + 5; if (sg > TT - 1) sg = TT - 1; \
      const int tg = dir ? (TT - 1 - sg) : sg; \
      HOLD = *(const float4*)(y0 + sgbase + (size_t)tg * 128); \
    } \
    short8 by0 = *(const short8*)&sY[slot][bcol][     quad * 8]; \
    short8 by1 = *(const short8*)&sY[slot][bcol][32 + quad * 8]; \
    short8 by2 = *(const short8*)&sY[slot][bcol][64 + quad * 8]; \
    short8 by3 = *(const short8*)&sY[slot][bcol][96 + quad * 8]; \
    short8 bh0 = *(const short8*)&sZ[p][m16][     quad * 8]; \
    short8 bh1 = *(const short8*)&sZ[p][m16][32 + quad * 8]; \
    short8 bh2 = *(const short8*)&sZ[p][m16][64 + quad * 8]; \
    short8 bh3 = *(const short8*)&sZ[p][m16][96 + quad * 8]; \
    f32x4 A0 = MF(aY[0][0], by0, biasv[0]); \
    f32x4 A1 = MF(aY[1][0], by0, biasv[1]); \
    f32x4 A2 = MF(aY[2][0], by0, biasv[2]); \
    f32x4 A3 = MF(aY[3][0], by0, biasv[3]); \
    A0 = MF(aY[0][1], by1, A0);  A1 = MF(aY[1][1], by1, A1); \
    A2 = MF(aY[2][1], by1, A2);  A3 = MF(aY[3][1], by1, A3); \
    f32x4 B0 = MF(aY[0][2], by2, z4); \
    f32x4 B1 = MF(aY[1][2], by2, z4); \
    f32x4 B2 = MF(aY[2][2], by2, z4); \
    f32x4 B3 = MF(aY[3][2], by2, z4); \
    B0 = MF(aY[0][3], by3, B0);  B1 = MF(aY[1][3], by3, B1); \
    B2 = MF(aY[2][3], by3, B2);  B3 = MF(aY[3][3], by3, B3); \
    A0 = MF(aH[0][0], bh0, A0);  A1 = MF(aH[1][0], bh0, A1); \
    A2 = MF(aH[2][0], bh0, A2);  A3 = MF(aH[3][0], bh0, A3); \
    A0 = MF(aH[0][1], bh1, A0);  A1 = MF(aH[1][1], bh1, A1); \
    A2 = MF(aH[2][1], bh1, A2);  A3 = MF(aH[3][1], bh1, A3); \
    B0 = MF(aH[0][2], bh2, B0);  B1 = MF(aH[1][2], bh2, B1); \
    B2 = MF(aH[2][2], bh2, B2);  B3 = MF(aH[3][2], bh2, B3); \
    B0 = MF(aH[0][3], bh3, B0);  B1 = MF(aH[1][3], bh3, B1); \
    B2 = MF(aH[2][3], bh3, B2);  B3 = MF(aH[3][3], bh3, B3); \
    f32x4 C0 = A0 + B0, C1 = A1 + B1, C2 = A2 + B2, C3 = A3 + B3; \
    NONLIN_WRITE4(C0, C1, C2, C3, p1); \
    if ((S) == TT - 1){ \
      hT[(size_t)(bbase + bcol) * 128 + dir * 64 + unit] = h; \
    } \
    lds_barrier(); \
  } while(0)

  for (int s = 0; s < TT; s += 2){
    L1STEP(s, hA);
    L1STEP(s + 1, hB);
  }
#undef L1STEP
}

// ==================== FC head ====================
__global__ __launch_bounds__(256, 1) void fc_kernel(
    const float* __restrict__ hT,
    const float* __restrict__ w1, const float* __restrict__ b1,
    const float* __restrict__ w2, const float* __restrict__ b2,
    float* __restrict__ out)
{
  __shared__ float sh[4][64];
  const int wave = threadIdx.x >> 6, lane = threadIdx.x & 63;
  const int b = blockIdx.x * 4 + wave;
  float acc = b1[lane];
  const float* hrow = hT + (size_t)b * 128;
  #pragma unroll
  for (int k = 0; k < 128; k += 4){
    float4 h4 = *(const float4*)(hrow + k);
    float4 w4 = *(const float4*)(w1 + lane * 128 + k);
    acc = fmaf(w4.x, h4.x, acc);
    acc = fmaf(w4.y, h4.y, acc);
    acc = fmaf(w4.z, h4.z, acc);
    acc = fmaf(w4.w, h4.w, acc);
  }
  sh[wave][lane] = fmaxf(acc, 0.f);
  __syncthreads();
  if (lane < 2){
    float a = b2[lane];
    #pragma unroll
    for (int k = 0; k < 64; k++) a = fmaf(w2[lane * 64 + k], sh[wave][k], a);
    out[(size_t)b * 2 + lane] = a;
  }
}

extern "C" void kernel_launch(void* const* d_in, const int* in_sizes, int n_in,
                              void* d_out, int out_size, void* d_ws, size_t ws_size,
                              hipStream_t stream){
  (void)in_sizes; (void)n_in; (void)out_size; (void)ws_size;
  const float* x     = (const float*)d_in[0];
  const float* Wih0f = (const float*)d_in[1];
  const float* Whh0f = (const float*)d_in[2];
  const float* bih0f = (const float*)d_in[3];
  const float* bhh0f = (const float*)d_in[4];
  const float* Wih0b = (const float*)d_in[5];
  const float* Whh0b = (const float*)d_in[6];
  const float* bih0b = (const float*)d_in[7];
  const float* bhh0b = (const float*)d_in[8];
  const float* Wih1f = (const float*)d_in[9];
  const float* Whh1f = (const float*)d_in[10];
  const float* bih1f = (const float*)d_in[11];
  const float* bhh1f = (const float*)d_in[12];
  const float* Wih1b = (const float*)d_in[13];
  const float* Whh1b = (const float*)d_in[14];
  const float* bih1b = (const float*)d_in[15];
  const float* bhh1b = (const float*)d_in[16];
  const float* fc1W  = (const float*)d_in[17];
  const float* fc1b  = (const float*)d_in[18];
  const float* fc2W  = (const float*)d_in[19];
  const float* fc2b  = (const float*)d_in[20];
  float* out = (float*)d_out;

  unsigned short* y0 = (unsigned short*)d_ws;                       // 134,217,728 B
  float* hT = (float*)((char*)d_ws + (size_t)1024 * TT * 128 * 2);

  dim3 grid(256, 2), block(256);
  lstm_l0<<<grid, block, 0, stream>>>(x, Wih0f, Whh0f, bih0f, bhh0f,
                                      Wih0b, Whh0b, bih0b, bhh0b, y0);
  lstm_l1<<<grid, block, 0, stream>>>(y0, Wih1f, Whh1f, bih1f, bhh1f,
                                      Wih1b, Whh1b, bih1b, bhh1b, hT);
  fc_kernel<<<dim3(256), dim3(256), 0, stream>>>(hT, fc1W, fc1b, fc2W, fc2b, out);
}

// Round 5
// 566.140 us; speedup vs baseline: 1.4923x; 1.4923x over previous
//
#include <hip/hip_runtime.h>
#include <stdint.h>

typedef __attribute__((ext_vector_type(8))) short short8;
typedef __attribute__((ext_vector_type(4))) float f32x4;

#define TT 512
#define LSTR 136   // sZ/sY row stride in ushorts: 272B -> uniform 8/bank for b128 reads
#define XS 516     // sX row stride in floats

static __device__ __forceinline__ uint32_t f2bf_u(float f){
  union { float f; uint32_t u; } v; v.f = f;
  return (v.u + 0x7fffu + ((v.u >> 16) & 1u)) >> 16;
}
static __device__ __forceinline__ short8 w8f32(const float* p){
  float4 a = *(const float4*)p;
  float4 b = *(const float4*)(p + 4);
  short8 r;
  r[0] = (short)f2bf_u(a.x); r[1] = (short)f2bf_u(a.y);
  r[2] = (short)f2bf_u(a.z); r[3] = (short)f2bf_u(a.w);
  r[4] = (short)f2bf_u(b.x); r[5] = (short)f2bf_u(b.y);
  r[6] = (short)f2bf_u(b.z); r[7] = (short)f2bf_u(b.w);
  return r;
}
// sigmoid via exp2+rcp: inf-safe (exp2->inf => rcp->0).
static __device__ __forceinline__ float sigx(float x){
  float e = __builtin_amdgcn_exp2f(-1.442695040888963f * x);
  return __builtin_amdgcn_rcpf(1.f + e);
}
// tanh(x) = 2*sigmoid(2x)-1: no clamp needed.
static __device__ __forceinline__ float tanhx(float x){
  float e = __builtin_amdgcn_exp2f(-2.885390081777927f * x);
  return fmaf(__builtin_amdgcn_rcpf(1.f + e), 2.f, -1.f);
}
// LDS-only barrier: waits ds ops, leaves global loads/stores in flight.
static __device__ __forceinline__ void lds_barrier(){
  asm volatile("s_waitcnt lgkmcnt(0)" ::: "memory");
  __builtin_amdgcn_s_barrier();
}
#define MF(A,B,C) __builtin_amdgcn_mfma_f32_16x16x32_bf16((A),(B),(C),0,0,0)

// Redistributed nonlinearity, bf16-only h state (no lo term): sZ rows 8-15
// duplicate rows 0-7, so MFMA C cols 8-15 hold real (dup) batch data and
// lanes m16>=8 use their own a1 registers (v_cndmask select). Each lane
// handles ONE (batch,unit) pair; h written as one bf16 to both dup rows.
#define NONLIN_WRITE(A0V, A1V, P1) do { \
    float g0_ = sel0 ? (A0V)[0] : (A1V)[0]; \
    float g1_ = sel0 ? (A0V)[1] : (A1V)[1]; \
    float g2_ = sel0 ? (A0V)[2] : (A1V)[2]; \
    float g3_ = sel0 ? (A0V)[3] : (A1V)[3]; \
    float ii_ = sigx(g0_), ff_ = sigx(g1_), gg_ = tanhx(g2_), oo_ = sigx(g3_); \
    c = fmaf(ff_, c, ii_ * gg_); \
    h = oo_ * tanhx(c); \
    { unsigned short hh_ = (unsigned short)f2bf_u(h); \
      sZ[P1][rw][colw]     = hh_; \
      sZ[P1][rw + 8][colw] = hh_; } \
  } while(0)

// ==================== Layer 0 ====================
// 512 thr / 8 waves; wave w owns rowtiles 2w,2w+1 (units 8w+q, 8w+4+q per lane quad q)
__global__ __launch_bounds__(512, 2) void lstm_l0(
    const float* __restrict__ x,   // [B][3][T]
    const float* __restrict__ Wih_f, const float* __restrict__ Whh_f,
    const float* __restrict__ bih_f, const float* __restrict__ bhh_f,
    const float* __restrict__ Wih_b, const float* __restrict__ Whh_b,
    const float* __restrict__ bih_b, const float* __restrict__ bhh_b,
    unsigned short* __restrict__ y0)  // [B][T][128] bf16
{
  const int tid = threadIdx.x;
  const int wv = tid >> 6, lane = tid & 63;
  const int quad = lane >> 4, m16 = lane & 15;
  const int dir = blockIdx.y;
  const int bbase = blockIdx.x * 8;
  const float* Wih = dir ? Wih_b : Wih_f;
  const float* Whh = dir ? Whh_b : Whh_f;
  const float* bih = dir ? bih_b : bih_f;
  const float* bhh = dir ? bhh_b : bhh_f;

  __shared__ __align__(16) unsigned short sZ[2][16][LSTR];
  __shared__ __align__(16) float sX[24 * XS];

  // A-frags: tile-row rho -> gate (rho&3), unit 4*rt+(rho>>2). K = 64 (h bf16).
  short8 aH[2][2], aX[2];
  f32x4 biasv[2];
  const int gm = (m16 & 3) * 64 + (m16 >> 2);
  #pragma unroll
  for (int i = 0; i < 2; i++){
    const int rt = 2 * wv + i;
    const int g = gm + 4 * rt;
    aH[i][0] = w8f32(Whh + g * 64 + quad * 8);
    aH[i][1] = w8f32(Whh + g * 64 + 32 + quad * 8);
    short8 ax = {0,0,0,0,0,0,0,0};
    if (quad == 0){
      ax[0] = (short)f2bf_u(Wih[g * 3 + 0]);
      ax[1] = (short)f2bf_u(Wih[g * 3 + 1]);
      ax[2] = (short)f2bf_u(Wih[g * 3 + 2]);
    }
    aX[i] = ax;
    const int gu = 4 * rt + quad;   // C reg r -> gate row r*64 + gu
    #pragma unroll
    for (int r = 0; r < 4; r++) biasv[i][r] = bih[r * 64 + gu] + bhh[r * 64 + gu];
  }

  for (int idx = tid; idx < 2 * 16 * LSTR; idx += 512)
    ((unsigned short*)sZ)[idx] = 0;
  for (int i4 = tid; i4 < 3072; i4 += 512){
    const int row = i4 >> 7, t4 = (i4 & 127) * 4;
    *(float4*)&sX[row * XS + t4] = *(const float4*)(x + (size_t)bbase * 1536 + row * 512 + t4);
  }
  __syncthreads();

  const int xrow = 3 * (m16 & 7);
  const bool sel0 = (m16 < 8);
  const int rw = m16 & 7;
  const int colw = 8 * wv + quad + ((m16 >> 3) << 2);  // u0 for m16<8, u1 for m16>=8
  float c = 0.f, h = 0.f;
  const f32x4 z4 = {0.f, 0.f, 0.f, 0.f};

#define L0STEP(S, P) do { \
    const int t_ = dir ? (TT - 1 - (S)) : (S); \
    short8 b0 = *(const short8*)&sZ[P][m16][     quad * 8]; \
    short8 b1 = *(const short8*)&sZ[P][m16][32 + quad * 8]; \
    short8 bx = {0,0,0,0,0,0,0,0}; \
    if (quad == 0){ \
      bx[0] = (short)f2bf_u(sX[xrow * XS + t_]); \
      bx[1] = (short)f2bf_u(sX[(xrow + 1) * XS + t_]); \
      bx[2] = (short)f2bf_u(sX[(xrow + 2) * XS + t_]); \
    } \
    if (wv == 7 && (S) > 0){ \
      const int tprev = dir ? (TT - (S)) : ((S) - 1); \
      const int br_ = lane >> 3, cc_ = lane & 7; \
      uint4 v_ = *(const uint4*)&sZ[P][br_][cc_ * 8]; \
      *(uint4*)(y0 + ((size_t)(bbase + br_) * TT + tprev) * 128 + dir * 64 + cc_ * 8) = v_; \
    } \
    f32x4 A0 = MF(aH[0][0], b0, biasv[0]); \
    f32x4 A1 = MF(aH[1][0], b0, biasv[1]); \
    A0 = MF(aH[0][1], b1, A0);  A1 = MF(aH[1][1], b1, A1); \
    f32x4 B0 = MF(aX[0], bx, z4); \
    f32x4 B1 = MF(aX[1], bx, z4); \
    f32x4 a0_ = A0 + B0, a1_ = A1 + B1; \
    NONLIN_WRITE(a0_, a1_, (1 - (P))); \
    lds_barrier(); \
  } while(0)

  for (int s = 0; s < TT; s += 2){
    L0STEP(s, 0);
    L0STEP(s + 1, 1);
  }
#undef L0STEP

  // final timestep's h (last write went to sZ[0])
  if (wv == 7){
    const int tl = dir ? 0 : (TT - 1);
    const int br = lane >> 3, cc = lane & 7;
    uint4 v = *(const uint4*)&sZ[0][br][cc * 8];
    *(uint4*)(y0 + ((size_t)(bbase + br) * TT + tl) * 128 + dir * 64 + cc * 8) = v;
  }
}

// ==================== Layer 1 ====================
// y0 staged through a 4-slot LDS ring by waves 0-1 (load once, share via LDS).
__global__ __launch_bounds__(512, 2) void lstm_l1(
    const unsigned short* __restrict__ y0,  // [B][T][128] bf16
    const float* __restrict__ Wih_f, const float* __restrict__ Whh_f,
    const float* __restrict__ bih_f, const float* __restrict__ bhh_f,
    const float* __restrict__ Wih_b, const float* __restrict__ Whh_b,
    const float* __restrict__ bih_b, const float* __restrict__ bhh_b,
    float* __restrict__ hT)                 // [B][128] fp32
{
  const int tid = threadIdx.x;
  const int wv = tid >> 6, lane = tid & 63;
  const int quad = lane >> 4, m16 = lane & 15;
  const int dir = blockIdx.y;
  const int bbase = blockIdx.x * 8;
  const float* Wih = dir ? Wih_b : Wih_f;
  const float* Whh = dir ? Whh_b : Whh_f;
  const float* bih = dir ? bih_b : bih_f;
  const float* bhh = dir ? bhh_b : bhh_f;

  __shared__ __align__(16) unsigned short sZ[2][16][LSTR];
  __shared__ __align__(16) unsigned short sY[4][8][LSTR];   // 4-slot y0 ring

  short8 aY[2][4], aH[2][2];
  f32x4 biasv[2];
  const int gm = (m16 & 3) * 64 + (m16 >> 2);
  #pragma unroll
  for (int i = 0; i < 2; i++){
    const int rt = 2 * wv + i;
    const int g = gm + 4 * rt;
    #pragma unroll
    for (int kt = 0; kt < 4; kt++) aY[i][kt] = w8f32(Wih + g * 128 + kt * 32 + quad * 8);
    aH[i][0] = w8f32(Whh + g * 64 + quad * 8);
    aH[i][1] = w8f32(Whh + g * 64 + 32 + quad * 8);
    const int gu = 4 * rt + quad;
    #pragma unroll
    for (int r = 0; r < 4; r++) biasv[i][r] = bih[r * 64 + gu] + bhh[r * 64 + gu];
  }

  for (int idx = tid; idx < 2 * 16 * LSTR; idx += 512)
    ((unsigned short*)sZ)[idx] = 0;

  // staging lanes (waves 0-1): task = tid in [0,128): row=tid>>4, chunk=tid&15
  const int srow = tid >> 4, schunk = tid & 15;
  const size_t sgbase = (size_t)(bbase + (srow & 7)) * TT * 128 + schunk * 8;
  float4 hA = make_float4(0.f,0.f,0.f,0.f), hB = make_float4(0.f,0.f,0.f,0.f);
  if (wv < 2){
    const int t0 = dir ? (TT-1) : 0, t1 = dir ? (TT-2) : 1, t2 = dir ? (TT-3) : 2;
    const int t3 = dir ? (TT-4) : 3, t4 = dir ? (TT-5) : 4;
    float4 v0 = *(const float4*)(y0 + sgbase + (size_t)t0 * 128);
    float4 v1 = *(const float4*)(y0 + sgbase + (size_t)t1 * 128);
    float4 v2 = *(const float4*)(y0 + sgbase + (size_t)t2 * 128);
    hA = *(const float4*)(y0 + sgbase + (size_t)t3 * 128);
    hB = *(const float4*)(y0 + sgbase + (size_t)t4 * 128);
    *(float4*)&sY[0][srow][schunk * 8] = v0;
    *(float4*)&sY[1][srow][schunk * 8] = v1;
    *(float4*)&sY[2][srow][schunk * 8] = v2;
  }
  __syncthreads();

  const int m8 = m16 & 7;
  const bool sel0 = (m16 < 8);
  const int rw = m16 & 7;
  const int colw = 8 * wv + quad + ((m16 >> 3) << 2);
  float c = 0.f, h = 0.f;
  const f32x4 z4 = {0.f, 0.f, 0.f, 0.f};

#define L1STEP(S, HOLD) do { \
    const int p = (S) & 1, p1 = p ^ 1, slot = (S) & 3; \
    if (wv < 2){ \
      *(float4*)&sY[((S) + 3) & 3][srow][schunk * 8] = HOLD; \
      int sg = (S) + 5; if (sg > TT - 1) sg = TT - 1; \
      const int tg = dir ? (TT - 1 - sg) : sg; \
      HOLD = *(const float4*)(y0 + sgbase + (size_t)tg * 128); \
    } \
    short8 by0 = *(const short8*)&sY[slot][m8][     quad * 8]; \
    short8 by1 = *(const short8*)&sY[slot][m8][32 + quad * 8]; \
    short8 by2 = *(const short8*)&sY[slot][m8][64 + quad * 8]; \
    short8 by3 = *(const short8*)&sY[slot][m8][96 + quad * 8]; \
    short8 bh0 = *(const short8*)&sZ[p][m16][     quad * 8]; \
    short8 bh1 = *(const short8*)&sZ[p][m16][32 + quad * 8]; \
    f32x4 A0 = MF(aY[0][0], by0, biasv[0]); \
    f32x4 A1 = MF(aY[1][0], by0, biasv[1]); \
    A0 = MF(aY[0][1], by1, A0);  A1 = MF(aY[1][1], by1, A1); \
    f32x4 B0 = MF(aY[0][2], by2, z4); \
    f32x4 B1 = MF(aY[1][2], by2, z4); \
    B0 = MF(aY[0][3], by3, B0);  B1 = MF(aY[1][3], by3, B1); \
    A0 = MF(aH[0][0], bh0, A0);  A1 = MF(aH[1][0], bh0, A1); \
    B0 = MF(aH[0][1], bh1, B0);  B1 = MF(aH[1][1], bh1, B1); \
    f32x4 a0_ = A0 + B0, a1_ = A1 + B1; \
    NONLIN_WRITE(a0_, a1_, p1); \
    if ((S) == TT - 1){ \
      hT[(size_t)(bbase + rw) * 128 + dir * 64 + colw] = h; \
    } \
    lds_barrier(); \
  } while(0)

  for (int s = 0; s < TT; s += 2){
    L1STEP(s, hA);
    L1STEP(s + 1, hB);
  }
#undef L1STEP
}

// ==================== FC head ====================
__global__ __launch_bounds__(256, 1) void fc_kernel(
    const float* __restrict__ hT,
    const float* __restrict__ w1, const float* __restrict__ b1,
    const float* __restrict__ w2, const float* __restrict__ b2,
    float* __restrict__ out)
{
  __shared__ float sh[4][64];
  const int wave = threadIdx.x >> 6, lane = threadIdx.x & 63;
  const int b = blockIdx.x * 4 + wave;
  float acc = b1[lane];
  const float* hrow = hT + (size_t)b * 128;
  #pragma unroll
  for (int k = 0; k < 128; k += 4){
    float4 h4 = *(const float4*)(hrow + k);
    float4 w4 = *(const float4*)(w1 + lane * 128 + k);
    acc = fmaf(w4.x, h4.x, acc);
    acc = fmaf(w4.y, h4.y, acc);
    acc = fmaf(w4.z, h4.z, acc);
    acc = fmaf(w4.w, h4.w, acc);
  }
  sh[wave][lane] = fmaxf(acc, 0.f);
  __syncthreads();
  if (lane < 2){
    float a = b2[lane];
    #pragma unroll
    for (int k = 0; k < 64; k++) a = fmaf(w2[lane * 64 + k], sh[wave][k], a);
    out[(size_t)b * 2 + lane] = a;
  }
}

extern "C" void kernel_launch(void* const* d_in, const int* in_sizes, int n_in,
                              void* d_out, int out_size, void* d_ws, size_t ws_size,
                              hipStream_t stream){
  (void)in_sizes; (void)n_in; (void)out_size; (void)ws_size;
  const float* x     = (const float*)d_in[0];
  const float* Wih0f = (const float*)d_in[1];
  const float* Whh0f = (const float*)d_in[2];
  const float* bih0f = (const float*)d_in[3];
  const float* bhh0f = (const float*)d_in[4];
  const float* Wih0b = (const float*)d_in[5];
  const float* Whh0b = (const float*)d_in[6];
  const float* bih0b = (const float*)d_in[7];
  const float* bhh0b = (const float*)d_in[8];
  const float* Wih1f = (const float*)d_in[9];
  const float* Whh1f = (const float*)d_in[10];
  const float* bih1f = (const float*)d_in[11];
  const float* bhh1f = (const float*)d_in[12];
  const float* Wih1b = (const float*)d_in[13];
  const float* Whh1b = (const float*)d_in[14];
  const float* bih1b = (const float*)d_in[15];
  const float* bhh1b = (const float*)d_in[16];
  const float* fc1W  = (const float*)d_in[17];
  const float* fc1b  = (const float*)d_in[18];
  const float* fc2W  = (const float*)d_in[19];
  const float* fc2b  = (const float*)d_in[20];
  float* out = (float*)d_out;

  unsigned short* y0 = (unsigned short*)d_ws;                       // 134,217,728 B
  float* hT = (float*)((char*)d_ws + (size_t)1024 * TT * 128 * 2);

  dim3 grid(128, 2), block(512);
  lstm_l0<<<grid, block, 0, stream>>>(x, Wih0f, Whh0f, bih0f, bhh0f,
                                      Wih0b, Whh0b, bih0b, bhh0b, y0);
  lstm_l1<<<grid, block, 0, stream>>>(y0, Wih1f, Whh1f, bih1f, bhh1f,
                                      Wih1b, Whh1b, bih1b, bhh1b, hT);
  fc_kernel<<<dim3(256), dim3(256), 0, stream>>>(hT, fc1W, fc1b, fc2W, fc2b, out);
}

// Round 6
// 560.376 us; speedup vs baseline: 1.5076x; 1.0103x over previous
//
#include <hip/hip_runtime.h>
#include <stdint.h>

typedef __attribute__((ext_vector_type(8))) short short8;
typedef __attribute__((ext_vector_type(4))) float f32x4;

#define TT 512
#define LSTR 136   // sZ/sY row stride in ushorts: 272B -> uniform 8/bank for b128 reads
#define XS 516     // sX row stride in floats

static __device__ __forceinline__ uint32_t f2bf_u(float f){
  union { float f; uint32_t u; } v; v.f = f;
  return (v.u + 0x7fffu + ((v.u >> 16) & 1u)) >> 16;
}
static __device__ __forceinline__ short8 w8f32(const float* p){
  float4 a = *(const float4*)p;
  float4 b = *(const float4*)(p + 4);
  short8 r;
  r[0] = (short)f2bf_u(a.x); r[1] = (short)f2bf_u(a.y);
  r[2] = (short)f2bf_u(a.z); r[3] = (short)f2bf_u(a.w);
  r[4] = (short)f2bf_u(b.x); r[5] = (short)f2bf_u(b.y);
  r[6] = (short)f2bf_u(b.z); r[7] = (short)f2bf_u(b.w);
  return r;
}
// sigmoid via exp2+rcp: inf-safe (exp2->inf => rcp->0).
static __device__ __forceinline__ float sigx(float x){
  float e = __builtin_amdgcn_exp2f(-1.442695040888963f * x);
  return __builtin_amdgcn_rcpf(1.f + e);
}
// tanh(x) = 2*sigmoid(2x)-1: no clamp needed.
static __device__ __forceinline__ float tanhx(float x){
  float e = __builtin_amdgcn_exp2f(-2.885390081777927f * x);
  return fmaf(__builtin_amdgcn_rcpf(1.f + e), 2.f, -1.f);
}
// LDS-only barrier: waits ds ops, leaves global loads/stores in flight.
static __device__ __forceinline__ void lds_barrier(){
  asm volatile("s_waitcnt lgkmcnt(0)" ::: "memory");
  __builtin_amdgcn_s_barrier();
}
#define MF(A,B,C) __builtin_amdgcn_mfma_f32_16x16x32_bf16((A),(B),(C),0,0,0)

// Redistributed nonlinearity, bf16-only h state: sZ rows 8-15 duplicate rows
// 0-7 (MFMA C cols 8-15 real dup data); lanes m16>=8 use their own A1 regs
// (v_cndmask). One (batch,unit) pair per lane; h -> bf16 to both dup rows.
#define NONLIN_WRITE(A0V, A1V, P1) do { \
    float g0_ = sel0 ? (A0V)[0] : (A1V)[0]; \
    float g1_ = sel0 ? (A0V)[1] : (A1V)[1]; \
    float g2_ = sel0 ? (A0V)[2] : (A1V)[2]; \
    float g3_ = sel0 ? (A0V)[3] : (A1V)[3]; \
    float ii_ = sigx(g0_), ff_ = sigx(g1_), gg_ = tanhx(g2_), oo_ = sigx(g3_); \
    c = fmaf(ff_, c, ii_ * gg_); \
    h = oo_ * tanhx(c); \
    { unsigned short hh_ = (unsigned short)f2bf_u(h); \
      sZ[P1][rw][colw]     = hh_; \
      sZ[P1][rw + 8][colw] = hh_; } \
  } while(0)

// ==================== Layer 0 ====================
// 512 thr / 8 waves; wave w owns units 8w+q (lanes m16<8) and 8w+4+q (m16>=8).
// Software-pipelined: FF (aX*bx for step s+1) computed PRE-barrier; only the
// 2-deep recurrent MFMA chain + nonlin sit between barrier and h-write.
__global__ __launch_bounds__(512, 2) void lstm_l0(
    const float* __restrict__ x,   // [B][3][T]
    const float* __restrict__ Wih_f, const float* __restrict__ Whh_f,
    const float* __restrict__ bih_f, const float* __restrict__ bhh_f,
    const float* __restrict__ Wih_b, const float* __restrict__ Whh_b,
    const float* __restrict__ bih_b, const float* __restrict__ bhh_b,
    unsigned short* __restrict__ y0)  // [B][T][128] bf16
{
  const int tid = threadIdx.x;
  const int wv = tid >> 6, lane = tid & 63;
  const int quad = lane >> 4, m16 = lane & 15;
  const int dir = blockIdx.y;
  const int bbase = blockIdx.x * 8;
  const float* Wih = dir ? Wih_b : Wih_f;
  const float* Whh = dir ? Whh_b : Whh_f;
  const float* bih = dir ? bih_b : bih_f;
  const float* bhh = dir ? bhh_b : bhh_f;

  __shared__ __align__(16) unsigned short sZ[2][16][LSTR];
  __shared__ __align__(16) float sX[24 * XS];

  short8 aH[2][2], aX[2];
  f32x4 biasv[2];
  const int gm = (m16 & 3) * 64 + (m16 >> 2);
  #pragma unroll
  for (int i = 0; i < 2; i++){
    const int rt = 2 * wv + i;
    const int g = gm + 4 * rt;
    aH[i][0] = w8f32(Whh + g * 64 + quad * 8);
    aH[i][1] = w8f32(Whh + g * 64 + 32 + quad * 8);
    short8 ax = {0,0,0,0,0,0,0,0};
    if (quad == 0){
      ax[0] = (short)f2bf_u(Wih[g * 3 + 0]);
      ax[1] = (short)f2bf_u(Wih[g * 3 + 1]);
      ax[2] = (short)f2bf_u(Wih[g * 3 + 2]);
    }
    aX[i] = ax;
    const int gu = 4 * rt + quad;
    #pragma unroll
    for (int r = 0; r < 4; r++) biasv[i][r] = bih[r * 64 + gu] + bhh[r * 64 + gu];
  }

  for (int idx = tid; idx < 2 * 16 * LSTR; idx += 512)
    ((unsigned short*)sZ)[idx] = 0;
  for (int i4 = tid; i4 < 3072; i4 += 512){
    const int row = i4 >> 7, t4 = (i4 & 127) * 4;
    *(float4*)&sX[row * XS + t4] = *(const float4*)(x + (size_t)bbase * 1536 + row * 512 + t4);
  }
  __syncthreads();

  const int xrow = 3 * (m16 & 7);
  const bool sel0 = (m16 < 8);
  const int rw = m16 & 7;
  const int colw = 8 * wv + quad + ((m16 >> 3) << 2);
  float c = 0.f, h = 0.f;

  // FF(0): FB = bias + Wih * x(t0)
  f32x4 FB0, FB1;
  {
    const int t0_ = dir ? (TT - 1) : 0;
    short8 bx = {0,0,0,0,0,0,0,0};
    if (quad == 0){
      bx[0] = (short)f2bf_u(sX[xrow * XS + t0_]);
      bx[1] = (short)f2bf_u(sX[(xrow + 1) * XS + t0_]);
      bx[2] = (short)f2bf_u(sX[(xrow + 2) * XS + t0_]);
    }
    FB0 = MF(aX[0], bx, biasv[0]);
    FB1 = MF(aX[1], bx, biasv[1]);
  }

#define L0STEP(S, P) do { \
    const int p1_ = (P) ^ 1; \
    short8 bh0 = *(const short8*)&sZ[P][m16][     quad * 8]; \
    short8 bh1 = *(const short8*)&sZ[P][m16][32 + quad * 8]; \
    if (lane < 8 && (S) > 0){ \
      const int tprev = dir ? (TT - (S)) : ((S) - 1); \
      uint4 v_ = *(const uint4*)&sZ[P][wv][lane * 8]; \
      *(uint4*)(y0 + ((size_t)(bbase + wv) * TT + tprev) * 128 + dir * 64 + lane * 8) = v_; \
    } \
    f32x4 A0 = MF(aH[0][0], bh0, FB0); \
    f32x4 A1 = MF(aH[1][0], bh0, FB1); \
    A0 = MF(aH[0][1], bh1, A0); \
    A1 = MF(aH[1][1], bh1, A1); \
    NONLIN_WRITE(A0, A1, p1_); \
    { int sn_ = (S) + 1; if (sn_ > TT - 1) sn_ = TT - 1; \
      const int tn_ = dir ? (TT - 1 - sn_) : sn_; \
      short8 bx = {0,0,0,0,0,0,0,0}; \
      if (quad == 0){ \
        bx[0] = (short)f2bf_u(sX[xrow * XS + tn_]); \
        bx[1] = (short)f2bf_u(sX[(xrow + 1) * XS + tn_]); \
        bx[2] = (short)f2bf_u(sX[(xrow + 2) * XS + tn_]); \
      } \
      FB0 = MF(aX[0], bx, biasv[0]); \
      FB1 = MF(aX[1], bx, biasv[1]); \
    } \
    __builtin_amdgcn_sched_barrier(0); \
    lds_barrier(); \
  } while(0)

  for (int s = 0; s < TT; s += 2){
    L0STEP(s, 0);
    L0STEP(s + 1, 1);
  }
#undef L0STEP

  // final timestep's h (last write went to sZ[0])
  if (lane < 8){
    const int tl = dir ? 0 : (TT - 1);
    uint4 v = *(const uint4*)&sZ[0][wv][lane * 8];
    *(uint4*)(y0 + ((size_t)(bbase + wv) * TT + tl) * 128 + dir * 64 + lane * 8) = v;
  }
}

// ==================== Layer 1 ====================
// Software-pipelined: FF (8 aY MFMAs for step s+1) computed PRE-barrier from
// the sY ring; post-barrier only 4 recurrent MFMAs + nonlin. Staging is
// distributed: wave w stages batch row w (lanes 0-15).
__global__ __launch_bounds__(512, 2) void lstm_l1(
    const unsigned short* __restrict__ y0,  // [B][T][128] bf16
    const float* __restrict__ Wih_f, const float* __restrict__ Whh_f,
    const float* __restrict__ bih_f, const float* __restrict__ bhh_f,
    const float* __restrict__ Wih_b, const float* __restrict__ Whh_b,
    const float* __restrict__ bih_b, const float* __restrict__ bhh_b,
    float* __restrict__ hT)                 // [B][128] fp32
{
  const int tid = threadIdx.x;
  const int wv = tid >> 6, lane = tid & 63;
  const int quad = lane >> 4, m16 = lane & 15;
  const int dir = blockIdx.y;
  const int bbase = blockIdx.x * 8;
  const float* Wih = dir ? Wih_b : Wih_f;
  const float* Whh = dir ? Whh_b : Whh_f;
  const float* bih = dir ? bih_b : bih_f;
  const float* bhh = dir ? bhh_b : bhh_f;

  __shared__ __align__(16) unsigned short sZ[2][16][LSTR];
  __shared__ __align__(16) unsigned short sY[4][8][LSTR];   // 4-slot y0 ring

  short8 aY[2][4], aH[2][2];
  f32x4 biasv[2];
  const int gm = (m16 & 3) * 64 + (m16 >> 2);
  #pragma unroll
  for (int i = 0; i < 2; i++){
    const int rt = 2 * wv + i;
    const int g = gm + 4 * rt;
    #pragma unroll
    for (int kt = 0; kt < 4; kt++) aY[i][kt] = w8f32(Wih + g * 128 + kt * 32 + quad * 8);
    aH[i][0] = w8f32(Whh + g * 64 + quad * 8);
    aH[i][1] = w8f32(Whh + g * 64 + 32 + quad * 8);
    const int gu = 4 * rt + quad;
    #pragma unroll
    for (int r = 0; r < 4; r++) biasv[i][r] = bih[r * 64 + gu] + bhh[r * 64 + gu];
  }

  for (int idx = tid; idx < 2 * 16 * LSTR; idx += 512)
    ((unsigned short*)sZ)[idx] = 0;

  // distributed staging: wave w stages batch row w, lanes 0-15 (16B chunks)
  const bool stager = (lane < 16);
  const size_t sgbase = (size_t)(bbase + wv) * TT * 128 + (size_t)lane * 8;
  float4 hA = make_float4(0.f,0.f,0.f,0.f), hB = make_float4(0.f,0.f,0.f,0.f);
  if (stager){
    const int t0 = dir ? (TT-1) : 0, t1 = dir ? (TT-2) : 1, t2 = dir ? (TT-3) : 2;
    const int t3 = dir ? (TT-4) : 3, t4 = dir ? (TT-5) : 4;
    float4 v0 = *(const float4*)(y0 + sgbase + (size_t)t0 * 128);
    float4 v1 = *(const float4*)(y0 + sgbase + (size_t)t1 * 128);
    float4 v2 = *(const float4*)(y0 + sgbase + (size_t)t2 * 128);
    hA = *(const float4*)(y0 + sgbase + (size_t)t3 * 128);
    hB = *(const float4*)(y0 + sgbase + (size_t)t4 * 128);
    *(float4*)&sY[0][wv][lane * 8] = v0;
    *(float4*)&sY[1][wv][lane * 8] = v1;
    *(float4*)&sY[2][wv][lane * 8] = v2;
  }
  __syncthreads();

  const int m8 = m16 & 7;
  const bool sel0 = (m16 < 8);
  const int rw = m16 & 7;
  const int colw = 8 * wv + quad + ((m16 >> 3) << 2);
  float c = 0.f, h = 0.f;

  // FF(0) from ring slot 0
  f32x4 FB0, FB1;
  {
    short8 by0 = *(const short8*)&sY[0][m8][     quad * 8];
    short8 by1 = *(const short8*)&sY[0][m8][32 + quad * 8];
    short8 by2 = *(const short8*)&sY[0][m8][64 + quad * 8];
    short8 by3 = *(const short8*)&sY[0][m8][96 + quad * 8];
    FB0 = MF(aY[0][0], by0, biasv[0]);
    FB1 = MF(aY[1][0], by0, biasv[1]);
    FB0 = MF(aY[0][1], by1, FB0);  FB1 = MF(aY[1][1], by1, FB1);
    FB0 = MF(aY[0][2], by2, FB0);  FB1 = MF(aY[1][2], by2, FB1);
    FB0 = MF(aY[0][3], by3, FB0);  FB1 = MF(aY[1][3], by3, FB1);
  }

#define L1STEP(S, P, HOLD) do { \
    const int p1_ = (P) ^ 1; \
    short8 bh0 = *(const short8*)&sZ[P][m16][     quad * 8]; \
    short8 bh1 = *(const short8*)&sZ[P][m16][32 + quad * 8]; \
    f32x4 A0 = MF(aH[0][0], bh0, FB0); \
    f32x4 A1 = MF(aH[1][0], bh0, FB1); \
    A0 = MF(aH[0][1], bh1, A0); \
    A1 = MF(aH[1][1], bh1, A1); \
    NONLIN_WRITE(A0, A1, p1_); \
    if ((S) == TT - 1){ \
      hT[(size_t)(bbase + rw) * 128 + dir * 64 + colw] = h; \
    } \
    if (stager){ \
      *(float4*)&sY[((S) + 3) & 3][wv][lane * 8] = HOLD; \
      int sg_ = (S) + 5; if (sg_ > TT - 1) sg_ = TT - 1; \
      const int tg_ = dir ? (TT - 1 - sg_) : sg_; \
      HOLD = *(const float4*)(y0 + sgbase + (size_t)tg_ * 128); \
    } \
    { const int sl_ = ((S) + 1) & 3; \
      short8 by0 = *(const short8*)&sY[sl_][m8][     quad * 8]; \
      short8 by1 = *(const short8*)&sY[sl_][m8][32 + quad * 8]; \
      short8 by2 = *(const short8*)&sY[sl_][m8][64 + quad * 8]; \
      short8 by3 = *(const short8*)&sY[sl_][m8][96 + quad * 8]; \
      FB0 = MF(aY[0][0], by0, biasv[0]); \
      FB1 = MF(aY[1][0], by0, biasv[1]); \
      FB0 = MF(aY[0][1], by1, FB0);  FB1 = MF(aY[1][1], by1, FB1); \
      FB0 = MF(aY[0][2], by2, FB0);  FB1 = MF(aY[1][2], by2, FB1); \
      FB0 = MF(aY[0][3], by3, FB0);  FB1 = MF(aY[1][3], by3, FB1); \
    } \
    __builtin_amdgcn_sched_barrier(0); \
    lds_barrier(); \
  } while(0)

  for (int s = 0; s < TT; s += 2){
    L1STEP(s, 0, hA);
    L1STEP(s + 1, 1, hB);
  }
#undef L1STEP
}

// ==================== FC head ====================
__global__ __launch_bounds__(256, 1) void fc_kernel(
    const float* __restrict__ hT,
    const float* __restrict__ w1, const float* __restrict__ b1,
    const float* __restrict__ w2, const float* __restrict__ b2,
    float* __restrict__ out)
{
  __shared__ float sh[4][64];
  const int wave = threadIdx.x >> 6, lane = threadIdx.x & 63;
  const int b = blockIdx.x * 4 + wave;
  float acc = b1[lane];
  const float* hrow = hT + (size_t)b * 128;
  #pragma unroll
  for (int k = 0; k < 128; k += 4){
    float4 h4 = *(const float4*)(hrow + k);
    float4 w4 = *(const float4*)(w1 + lane * 128 + k);
    acc = fmaf(w4.x, h4.x, acc);
    acc = fmaf(w4.y, h4.y, acc);
    acc = fmaf(w4.z, h4.z, acc);
    acc = fmaf(w4.w, h4.w, acc);
  }
  sh[wave][lane] = fmaxf(acc, 0.f);
  __syncthreads();
  if (lane < 2){
    float a = b2[lane];
    #pragma unroll
    for (int k = 0; k < 64; k++) a = fmaf(w2[lane * 64 + k], sh[wave][k], a);
    out[(size_t)b * 2 + lane] = a;
  }
}

extern "C" void kernel_launch(void* const* d_in, const int* in_sizes, int n_in,
                              void* d_out, int out_size, void* d_ws, size_t ws_size,
                              hipStream_t stream){
  (void)in_sizes; (void)n_in; (void)out_size; (void)ws_size;
  const float* x     = (const float*)d_in[0];
  const float* Wih0f = (const float*)d_in[1];
  const float* Whh0f = (const float*)d_in[2];
  const float* bih0f = (const float*)d_in[3];
  const float* bhh0f = (const float*)d_in[4];
  const float* Wih0b = (const float*)d_in[5];
  const float* Whh0b = (const float*)d_in[6];
  const float* bih0b = (const float*)d_in[7];
  const float* bhh0b = (const float*)d_in[8];
  const float* Wih1f = (const float*)d_in[9];
  const float* Whh1f = (const float*)d_in[10];
  const float* bih1f = (const float*)d_in[11];
  const float* bhh1f = (const float*)d_in[12];
  const float* Wih1b = (const float*)d_in[13];
  const float* Whh1b = (const float*)d_in[14];
  const float* bih1b = (const float*)d_in[15];
  const float* bhh1b = (const float*)d_in[16];
  const float* fc1W  = (const float*)d_in[17];
  const float* fc1b  = (const float*)d_in[18];
  const float* fc2W  = (const float*)d_in[19];
  const float* fc2b  = (const float*)d_in[20];
  float* out = (float*)d_out;

  unsigned short* y0 = (unsigned short*)d_ws;                       // 134,217,728 B
  float* hT = (float*)((char*)d_ws + (size_t)1024 * TT * 128 * 2);

  dim3 grid(128, 2), block(512);
  lstm_l0<<<grid, block, 0, stream>>>(x, Wih0f, Whh0f, bih0f, bhh0f,
                                      Wih0b, Whh0b, bih0b, bhh0b, y0);
  lstm_l1<<<grid, block, 0, stream>>>(y0, Wih1f, Whh1f, bih1f, bhh1f,
                                      Wih1b, Whh1b, bih1b, bhh1b, hT);
  fc_kernel<<<dim3(256), dim3(256), 0, stream>>>(hT, fc1W, fc1b, fc2W, fc2b, out);
}

// Round 7
// 546.631 us; speedup vs baseline: 1.5455x; 1.0251x over previous
//
#include <hip/hip_runtime.h>
#include <stdint.h>

typedef __attribute__((ext_vector_type(8))) short short8;
typedef __attribute__((ext_vector_type(4))) float f32x4;

#define TT 512
#define LSTR 136   // sZ/sY row stride in ushorts: 272B -> spread banks
#define XS 516     // sX row stride in floats

static __device__ __forceinline__ uint32_t f2bf_u(float f){
  union { float f; uint32_t u; } v; v.f = f;
  return (v.u + 0x7fffu + ((v.u >> 16) & 1u)) >> 16;
}
static __device__ __forceinline__ short8 w8f32(const float* p){
  float4 a = *(const float4*)p;
  float4 b = *(const float4*)(p + 4);
  short8 r;
  r[0] = (short)f2bf_u(a.x); r[1] = (short)f2bf_u(a.y);
  r[2] = (short)f2bf_u(a.z); r[3] = (short)f2bf_u(a.w);
  r[4] = (short)f2bf_u(b.x); r[5] = (short)f2bf_u(b.y);
  r[6] = (short)f2bf_u(b.z); r[7] = (short)f2bf_u(b.w);
  return r;
}
// sigmoid via exp2+rcp: inf-safe (exp2->inf => rcp->0).
static __device__ __forceinline__ float sigx(float x){
  float e = __builtin_amdgcn_exp2f(-1.442695040888963f * x);
  return __builtin_amdgcn_rcpf(1.f + e);
}
// tanh(x) = 2*sigmoid(2x)-1: no clamp needed.
static __device__ __forceinline__ float tanhx(float x){
  float e = __builtin_amdgcn_exp2f(-2.885390081777927f * x);
  return fmaf(__builtin_amdgcn_rcpf(1.f + e), 2.f, -1.f);
}
// LDS-only barrier: waits ds ops, leaves global loads/stores in flight.
static __device__ __forceinline__ void lds_barrier(){
  asm volatile("s_waitcnt lgkmcnt(0)" ::: "memory");
  __builtin_amdgcn_s_barrier();
}
#define MF(A,B,C) __builtin_amdgcn_mfma_f32_16x16x32_bf16((A),(B),(C),0,0,0)

// Redistributed nonlinearity, bf16 h, 8-row sZ: B cols 8-15 get batch data by
// READING row m16&7 (same-address broadcast, free) instead of duplicated
// storage. Lanes m16>=8 use their own A1 regs (v_cndmask). One (batch,unit)
// pair per lane; single ds_write_b16 per step.
#define NONLIN_WRITE(A0V, A1V, P1) do { \
    float g0_ = sel0 ? (A0V)[0] : (A1V)[0]; \
    float g1_ = sel0 ? (A0V)[1] : (A1V)[1]; \
    float g2_ = sel0 ? (A0V)[2] : (A1V)[2]; \
    float g3_ = sel0 ? (A0V)[3] : (A1V)[3]; \
    float ii_ = sigx(g0_), ff_ = sigx(g1_), gg_ = tanhx(g2_), oo_ = sigx(g3_); \
    c = fmaf(ff_, c, ii_ * gg_); \
    h = oo_ * tanhx(c); \
    sZ[P1][m8][colw] = (unsigned short)f2bf_u(h); \
  } while(0)

// ==================== Layer 0 ====================
// 512 thr / 8 waves; wave w owns units 8w+q (m16<8) and 8w+4+q (m16>=8).
// Issue order per step: ds reads -> rec MFMA -> FF MFMA (next step) ->
// sched_barrier -> nonlin. FF queues in the matrix pipe under nonlin's VALU.
__global__ __launch_bounds__(512, 2) void lstm_l0(
    const float* __restrict__ x,   // [B][3][T]
    const float* __restrict__ Wih_f, const float* __restrict__ Whh_f,
    const float* __restrict__ bih_f, const float* __restrict__ bhh_f,
    const float* __restrict__ Wih_b, const float* __restrict__ Whh_b,
    const float* __restrict__ bih_b, const float* __restrict__ bhh_b,
    unsigned short* __restrict__ y0)  // [B][T][128] bf16
{
  const int tid = threadIdx.x;
  const int wv = tid >> 6, lane = tid & 63;
  const int quad = lane >> 4, m16 = lane & 15;
  const int dir = blockIdx.y;
  const int bbase = blockIdx.x * 8;
  const float* Wih = dir ? Wih_b : Wih_f;
  const float* Whh = dir ? Whh_b : Whh_f;
  const float* bih = dir ? bih_b : bih_f;
  const float* bhh = dir ? bhh_b : bhh_f;

  __shared__ __align__(16) unsigned short sZ[2][8][LSTR];
  __shared__ __align__(16) float sX[24 * XS];

  short8 aH[2][2], aX[2];
  f32x4 biasv[2];
  const int gm = (m16 & 3) * 64 + (m16 >> 2);
  #pragma unroll
  for (int i = 0; i < 2; i++){
    const int rt = 2 * wv + i;
    const int g = gm + 4 * rt;
    aH[i][0] = w8f32(Whh + g * 64 + quad * 8);
    aH[i][1] = w8f32(Whh + g * 64 + 32 + quad * 8);
    short8 ax = {0,0,0,0,0,0,0,0};
    if (quad == 0){
      ax[0] = (short)f2bf_u(Wih[g * 3 + 0]);
      ax[1] = (short)f2bf_u(Wih[g * 3 + 1]);
      ax[2] = (short)f2bf_u(Wih[g * 3 + 2]);
    }
    aX[i] = ax;
    const int gu = 4 * rt + quad;
    #pragma unroll
    for (int r = 0; r < 4; r++) biasv[i][r] = bih[r * 64 + gu] + bhh[r * 64 + gu];
  }

  for (int idx = tid; idx < 2 * 8 * LSTR; idx += 512)
    ((unsigned short*)sZ)[idx] = 0;
  for (int i4 = tid; i4 < 3072; i4 += 512){
    const int row = i4 >> 7, t4 = (i4 & 127) * 4;
    *(float4*)&sX[row * XS + t4] = *(const float4*)(x + (size_t)bbase * 1536 + row * 512 + t4);
  }
  __syncthreads();

  const int m8 = m16 & 7;
  const int xrow = 3 * m8;
  const bool sel0 = (m16 < 8);
  const int colw = 8 * wv + quad + ((m16 >> 3) << 2);
  float c = 0.f, h = 0.f;

  // FF(0): FB = bias + Wih * x(t0)
  f32x4 FBa0, FBa1, FBb0, FBb1;
  {
    const int t0_ = dir ? (TT - 1) : 0;
    short8 bx = {0,0,0,0,0,0,0,0};
    if (quad == 0){
      bx[0] = (short)f2bf_u(sX[xrow * XS + t0_]);
      bx[1] = (short)f2bf_u(sX[(xrow + 1) * XS + t0_]);
      bx[2] = (short)f2bf_u(sX[(xrow + 2) * XS + t0_]);
    }
    FBa0 = MF(aX[0], bx, biasv[0]);
    FBa1 = MF(aX[1], bx, biasv[1]);
  }

#define L0STEP(S, P, FC0, FC1, FN0, FN1) do { \
    const int p1_ = (P) ^ 1; \
    short8 bh0 = *(const short8*)&sZ[P][m8][     quad * 8]; \
    short8 bh1 = *(const short8*)&sZ[P][m8][32 + quad * 8]; \
    if (lane < 8 && (S) > 0){ \
      const int tprev = dir ? (TT - (S)) : ((S) - 1); \
      uint4 v_ = *(const uint4*)&sZ[P][wv][lane * 8]; \
      *(uint4*)(y0 + ((size_t)(bbase + wv) * TT + tprev) * 128 + dir * 64 + lane * 8) = v_; \
    } \
    f32x4 A0 = MF(aH[0][0], bh0, FC0); \
    f32x4 A1 = MF(aH[1][0], bh0, FC1); \
    A0 = MF(aH[0][1], bh1, A0); \
    A1 = MF(aH[1][1], bh1, A1); \
    { int sn_ = (S) + 1; if (sn_ > TT - 1) sn_ = TT - 1; \
      const int tn_ = dir ? (TT - 1 - sn_) : sn_; \
      short8 bx_ = {0,0,0,0,0,0,0,0}; \
      if (quad == 0){ \
        bx_[0] = (short)f2bf_u(sX[xrow * XS + tn_]); \
        bx_[1] = (short)f2bf_u(sX[(xrow + 1) * XS + tn_]); \
        bx_[2] = (short)f2bf_u(sX[(xrow + 2) * XS + tn_]); \
      } \
      FN0 = MF(aX[0], bx_, biasv[0]); \
      FN1 = MF(aX[1], bx_, biasv[1]); \
    } \
    __builtin_amdgcn_sched_barrier(0); \
    NONLIN_WRITE(A0, A1, p1_); \
    __builtin_amdgcn_sched_barrier(0); \
    lds_barrier(); \
  } while(0)

  for (int s = 0; s < TT; s += 2){
    L0STEP(s, 0, FBa0, FBa1, FBb0, FBb1);
    L0STEP(s + 1, 1, FBb0, FBb1, FBa0, FBa1);
  }
#undef L0STEP

  // final timestep's h (last write went to sZ[0])
  if (lane < 8){
    const int tl = dir ? 0 : (TT - 1);
    uint4 v = *(const uint4*)&sZ[0][wv][lane * 8];
    *(uint4*)(y0 + ((size_t)(bbase + wv) * TT + tl) * 128 + dir * 64 + lane * 8) = v;
  }
}

// ==================== Layer 1 ====================
// Same issue-order pipeline; y0 via 4-slot LDS ring with distributed staging
// (wave w stages batch row w, lanes 0-15).
__global__ __launch_bounds__(512, 2) void lstm_l1(
    const unsigned short* __restrict__ y0,  // [B][T][128] bf16
    const float* __restrict__ Wih_f, const float* __restrict__ Whh_f,
    const float* __restrict__ bih_f, const float* __restrict__ bhh_f,
    const float* __restrict__ Wih_b, const float* __restrict__ Whh_b,
    const float* __restrict__ bih_b, const float* __restrict__ bhh_b,
    float* __restrict__ hT)                 // [B][128] fp32
{
  const int tid = threadIdx.x;
  const int wv = tid >> 6, lane = tid & 63;
  const int quad = lane >> 4, m16 = lane & 15;
  const int dir = blockIdx.y;
  const int bbase = blockIdx.x * 8;
  const float* Wih = dir ? Wih_b : Wih_f;
  const float* Whh = dir ? Whh_b : Whh_f;
  const float* bih = dir ? bih_b : bih_f;
  const float* bhh = dir ? bhh_b : bhh_f;

  __shared__ __align__(16) unsigned short sZ[2][8][LSTR];
  __shared__ __align__(16) unsigned short sY[4][8][LSTR];   // 4-slot y0 ring

  short8 aY[2][4], aH[2][2];
  f32x4 biasv[2];
  const int gm = (m16 & 3) * 64 + (m16 >> 2);
  #pragma unroll
  for (int i = 0; i < 2; i++){
    const int rt = 2 * wv + i;
    const int g = gm + 4 * rt;
    #pragma unroll
    for (int kt = 0; kt < 4; kt++) aY[i][kt] = w8f32(Wih + g * 128 + kt * 32 + quad * 8);
    aH[i][0] = w8f32(Whh + g * 64 + quad * 8);
    aH[i][1] = w8f32(Whh + g * 64 + 32 + quad * 8);
    const int gu = 4 * rt + quad;
    #pragma unroll
    for (int r = 0; r < 4; r++) biasv[i][r] = bih[r * 64 + gu] + bhh[r * 64 + gu];
  }

  for (int idx = tid; idx < 2 * 8 * LSTR; idx += 512)
    ((unsigned short*)sZ)[idx] = 0;

  // distributed staging: wave w stages batch row w, lanes 0-15 (16B chunks)
  const bool stager = (lane < 16);
  const size_t sgbase = (size_t)(bbase + wv) * TT * 128 + (size_t)lane * 8;
  float4 hA = make_float4(0.f,0.f,0.f,0.f), hB = make_float4(0.f,0.f,0.f,0.f);
  if (stager){
    const int t0 = dir ? (TT-1) : 0, t1 = dir ? (TT-2) : 1, t2 = dir ? (TT-3) : 2;
    const int t3 = dir ? (TT-4) : 3, t4 = dir ? (TT-5) : 4;
    float4 v0 = *(const float4*)(y0 + sgbase + (size_t)t0 * 128);
    float4 v1 = *(const float4*)(y0 + sgbase + (size_t)t1 * 128);
    float4 v2 = *(const float4*)(y0 + sgbase + (size_t)t2 * 128);
    hA = *(const float4*)(y0 + sgbase + (size_t)t3 * 128);
    hB = *(const float4*)(y0 + sgbase + (size_t)t4 * 128);
    *(float4*)&sY[0][wv][lane * 8] = v0;
    *(float4*)&sY[1][wv][lane * 8] = v1;
    *(float4*)&sY[2][wv][lane * 8] = v2;
  }
  __syncthreads();

  const int m8 = m16 & 7;
  const bool sel0 = (m16 < 8);
  const int colw = 8 * wv + quad + ((m16 >> 3) << 2);
  float c = 0.f, h = 0.f;

  // FF(0) from ring slot 0
  f32x4 FBa0, FBa1, FBb0, FBb1;
  {
    short8 by0 = *(const short8*)&sY[0][m8][     quad * 8];
    short8 by1 = *(const short8*)&sY[0][m8][32 + quad * 8];
    short8 by2 = *(const short8*)&sY[0][m8][64 + quad * 8];
    short8 by3 = *(const short8*)&sY[0][m8][96 + quad * 8];
    FBa0 = MF(aY[0][0], by0, biasv[0]);
    FBa1 = MF(aY[1][0], by0, biasv[1]);
    FBa0 = MF(aY[0][1], by1, FBa0);  FBa1 = MF(aY[1][1], by1, FBa1);
    FBa0 = MF(aY[0][2], by2, FBa0);  FBa1 = MF(aY[1][2], by2, FBa1);
    FBa0 = MF(aY[0][3], by3, FBa0);  FBa1 = MF(aY[1][3], by3, FBa1);
  }

#define L1STEP(S, P, HOLD, FC0, FC1, FN0, FN1) do { \
    const int p1_ = (P) ^ 1; const int sl_ = ((S) + 1) & 3; \
    short8 bh0 = *(const short8*)&sZ[P][m8][     quad * 8]; \
    short8 bh1 = *(const short8*)&sZ[P][m8][32 + quad * 8]; \
    short8 by0 = *(const short8*)&sY[sl_][m8][     quad * 8]; \
    short8 by1 = *(const short8*)&sY[sl_][m8][32 + quad * 8]; \
    short8 by2 = *(const short8*)&sY[sl_][m8][64 + quad * 8]; \
    short8 by3 = *(const short8*)&sY[sl_][m8][96 + quad * 8]; \
    f32x4 A0 = MF(aH[0][0], bh0, FC0); \
    f32x4 A1 = MF(aH[1][0], bh0, FC1); \
    A0 = MF(aH[0][1], bh1, A0); \
    A1 = MF(aH[1][1], bh1, A1); \
    FN0 = MF(aY[0][0], by0, biasv[0]); \
    FN1 = MF(aY[1][0], by0, biasv[1]); \
    FN0 = MF(aY[0][1], by1, FN0);  FN1 = MF(aY[1][1], by1, FN1); \
    FN0 = MF(aY[0][2], by2, FN0);  FN1 = MF(aY[1][2], by2, FN1); \
    FN0 = MF(aY[0][3], by3, FN0);  FN1 = MF(aY[1][3], by3, FN1); \
    __builtin_amdgcn_sched_barrier(0); \
    NONLIN_WRITE(A0, A1, p1_); \
    if ((S) == TT - 1){ \
      hT[(size_t)(bbase + m8) * 128 + dir * 64 + colw] = h; \
    } \
    if (stager){ \
      *(float4*)&sY[((S) + 3) & 3][wv][lane * 8] = HOLD; \
      int sg_ = (S) + 5; if (sg_ > TT - 1) sg_ = TT - 1; \
      const int tg_ = dir ? (TT - 1 - sg_) : sg_; \
      HOLD = *(const float4*)(y0 + sgbase + (size_t)tg_ * 128); \
    } \
    __builtin_amdgcn_sched_barrier(0); \
    lds_barrier(); \
  } while(0)

  for (int s = 0; s < TT; s += 2){
    L1STEP(s, 0, hA, FBa0, FBa1, FBb0, FBb1);
    L1STEP(s + 1, 1, hB, FBb0, FBb1, FBa0, FBa1);
  }
#undef L1STEP
}

// ==================== FC head ====================
__global__ __launch_bounds__(256, 1) void fc_kernel(
    const float* __restrict__ hT,
    const float* __restrict__ w1, const float* __restrict__ b1,
    const float* __restrict__ w2, const float* __restrict__ b2,
    float* __restrict__ out)
{
  __shared__ float sh[4][64];
  const int wave = threadIdx.x >> 6, lane = threadIdx.x & 63;
  const int b = blockIdx.x * 4 + wave;
  float acc = b1[lane];
  const float* hrow = hT + (size_t)b * 128;
  #pragma unroll
  for (int k = 0; k < 128; k += 4){
    float4 h4 = *(const float4*)(hrow + k);
    float4 w4 = *(const float4*)(w1 + lane * 128 + k);
    acc = fmaf(w4.x, h4.x, acc);
    acc = fmaf(w4.y, h4.y, acc);
    acc = fmaf(w4.z, h4.z, acc);
    acc = fmaf(w4.w, h4.w, acc);
  }
  sh[wave][lane] = fmaxf(acc, 0.f);
  __syncthreads();
  if (lane < 2){
    float a = b2[lane];
    #pragma unroll
    for (int k = 0; k < 64; k++) a = fmaf(w2[lane * 64 + k], sh[wave][k], a);
    out[(size_t)b * 2 + lane] = a;
  }
}

extern "C" void kernel_launch(void* const* d_in, const int* in_sizes, int n_in,
                              void* d_out, int out_size, void* d_ws, size_t ws_size,
                              hipStream_t stream){
  (void)in_sizes; (void)n_in; (void)out_size; (void)ws_size;
  const float* x     = (const float*)d_in[0];
  const float* Wih0f = (const float*)d_in[1];
  const float* Whh0f = (const float*)d_in[2];
  const float* bih0f = (const float*)d_in[3];
  const float* bhh0f = (const float*)d_in[4];
  const float* Wih0b = (const float*)d_in[5];
  const float* Whh0b = (const float*)d_in[6];
  const float* bih0b = (const float*)d_in[7];
  const float* bhh0b = (const float*)d_in[8];
  const float* Wih1f = (const float*)d_in[9];
  const float* Whh1f = (const float*)d_in[10];
  const float* bih1f = (const float*)d_in[11];
  const float* bhh1f = (const float*)d_in[12];
  const float* Wih1b = (const float*)d_in[13];
  const float* Whh1b = (const float*)d_in[14];
  const float* bih1b = (const float*)d_in[15];
  const float* bhh1b = (const float*)d_in[16];
  const float* fc1W  = (const float*)d_in[17];
  const float* fc1b  = (const float*)d_in[18];
  const float* fc2W  = (const float*)d_in[19];
  const float* fc2b  = (const float*)d_in[20];
  float* out = (float*)d_out;

  unsigned short* y0 = (unsigned short*)d_ws;                       // 134,217,728 B
  float* hT = (float*)((char*)d_ws + (size_t)1024 * TT * 128 * 2);

  dim3 grid(128, 2), block(512);
  lstm_l0<<<grid, block, 0, stream>>>(x, Wih0f, Whh0f, bih0f, bhh0f,
                                      Wih0b, Whh0b, bih0b, bhh0b, y0);
  lstm_l1<<<grid, block, 0, stream>>>(y0, Wih1f, Whh1f, bih1f, bhh1f,
                                      Wih1b, Whh1b, bih1b, bhh1b, hT);
  fc_kernel<<<dim3(256), dim3(256), 0, stream>>>(hT, fc1W, fc1b, fc2W, fc2b, out);
}

// Round 9
// 530.603 us; speedup vs baseline: 1.5922x; 1.0302x over previous
//
#include <hip/hip_runtime.h>
#include <stdint.h>

typedef __attribute__((ext_vector_type(8))) short short8;
typedef __attribute__((ext_vector_type(4))) float f32x4;

#define TT 512
#define LSTR 136   // sZ/sY row stride in ushorts: 272B -> spread banks
#define XS 516     // sX row stride in floats

static __device__ __forceinline__ uint32_t f2bf_u(float f){
  union { float f; uint32_t u; } v; v.f = f;
  return (v.u + 0x7fffu + ((v.u >> 16) & 1u)) >> 16;
}
static __device__ __forceinline__ short8 w8f32(const float* p){
  float4 a = *(const float4*)p;
  float4 b = *(const float4*)(p + 4);
  short8 r;
  r[0] = (short)f2bf_u(a.x); r[1] = (short)f2bf_u(a.y);
  r[2] = (short)f2bf_u(a.z); r[3] = (short)f2bf_u(a.w);
  r[4] = (short)f2bf_u(b.x); r[5] = (short)f2bf_u(b.y);
  r[6] = (short)f2bf_u(b.z); r[7] = (short)f2bf_u(b.w);
  return r;
}
// sigmoid via exp2+rcp: inf-safe (exp2->inf => rcp->0).
static __device__ __forceinline__ float sigx(float x){
  float e = __builtin_amdgcn_exp2f(-1.442695040888963f * x);
  return __builtin_amdgcn_rcpf(1.f + e);
}
// tanh(x) = 2*sigmoid(2x)-1: no clamp needed.
static __device__ __forceinline__ float tanhx(float x){
  float e = __builtin_amdgcn_exp2f(-2.885390081777927f * x);
  return fmaf(__builtin_amdgcn_rcpf(1.f + e), 2.f, -1.f);
}
// LDS-only barrier: waits ds ops, leaves global loads/stores in flight.
static __device__ __forceinline__ void lds_barrier(){
  asm volatile("s_waitcnt lgkmcnt(0)" ::: "memory");
  __builtin_amdgcn_s_barrier();
}
#define MF(A,B,C) __builtin_amdgcn_mfma_f32_16x16x32_bf16((A),(B),(C),0,0,0)

// Redistributed nonlinearity, bf16 h, 8-row sZ (cols 8-15 read row m16&7 as
// same-address broadcast). Lanes m16>=8 use their own A1 regs (v_cndmask).
// One (batch,unit) pair per lane; single ds_write_b16 per step.
#define NONLIN_WRITE(A0V, A1V, P1) do { \
    float g0_ = sel0 ? (A0V)[0] : (A1V)[0]; \
    float g1_ = sel0 ? (A0V)[1] : (A1V)[1]; \
    float g2_ = sel0 ? (A0V)[2] : (A1V)[2]; \
    float g3_ = sel0 ? (A0V)[3] : (A1V)[3]; \
    float ii_ = sigx(g0_), ff_ = sigx(g1_), gg_ = tanhx(g2_), oo_ = sigx(g3_); \
    c = fmaf(ff_, c, ii_ * gg_); \
    h = oo_ * tanhx(c); \
    sZ[P1][m8][colw] = (unsigned short)f2bf_u(h); \
  } while(0)

// ==================== Layer 0 ====================
// FF (Wih*x, K=3) done on the VALU: 24 fmaf/lane into FB regs, prefetched for
// step s+1 while step s's rec MFMAs drain. No bf16 x-packing, no FF MFMA.
__global__ __launch_bounds__(512, 2) void lstm_l0(
    const float* __restrict__ x,   // [B][3][T]
    const float* __restrict__ Wih_f, const float* __restrict__ Whh_f,
    const float* __restrict__ bih_f, const float* __restrict__ bhh_f,
    const float* __restrict__ Wih_b, const float* __restrict__ Whh_b,
    const float* __restrict__ bih_b, const float* __restrict__ bhh_b,
    unsigned short* __restrict__ y0)  // [B][T][128] bf16
{
  const int tid = threadIdx.x;
  const int wv = tid >> 6, lane = tid & 63;
  const int quad = lane >> 4, m16 = lane & 15;
  const int dir = blockIdx.y;
  const int bbase = blockIdx.x * 8;
  const float* Wih = dir ? Wih_b : Wih_f;
  const float* Whh = dir ? Whh_b : Whh_f;
  const float* bih = dir ? bih_b : bih_f;
  const float* bhh = dir ? bhh_b : bhh_f;

  __shared__ __align__(16) unsigned short sZ[2][8][LSTR];
  __shared__ __align__(16) float sX[24 * XS];

  short8 aH[2][2];
  f32x4 biasv[2];
  float Wf[2][4][3];   // per-lane FF weights: chain i, gate r, input d
  const int gm = (m16 & 3) * 64 + (m16 >> 2);
  #pragma unroll
  for (int i = 0; i < 2; i++){
    const int rt = 2 * wv + i;
    const int g = gm + 4 * rt;
    aH[i][0] = w8f32(Whh + g * 64 + quad * 8);
    aH[i][1] = w8f32(Whh + g * 64 + 32 + quad * 8);
    const int gu = 4 * rt + quad;
    #pragma unroll
    for (int r = 0; r < 4; r++){
      biasv[i][r] = bih[r * 64 + gu] + bhh[r * 64 + gu];
      #pragma unroll
      for (int d = 0; d < 3; d++) Wf[i][r][d] = Wih[(r * 64 + gu) * 3 + d];
    }
  }

  for (int idx = tid; idx < 2 * 8 * LSTR; idx += 512)
    ((unsigned short*)sZ)[idx] = 0;
  for (int i4 = tid; i4 < 3072; i4 += 512){
    const int row = i4 >> 7, t4 = (i4 & 127) * 4;
    *(float4*)&sX[row * XS + t4] = *(const float4*)(x + (size_t)bbase * 1536 + row * 512 + t4);
  }
  __syncthreads();

  const int m8 = m16 & 7;
  const int xrow = 3 * m8;
  const bool sel0 = (m16 < 8);
  const int colw = 8 * wv + quad + ((m16 >> 3) << 2);
  float c = 0.f, h = 0.f;

  // FF(t) via VALU into (F0,F1)
#define FFCOMP(F0, F1, TIDX) do { \
    float x0_ = sX[xrow * XS + (TIDX)]; \
    float x1_ = sX[(xrow + 1) * XS + (TIDX)]; \
    float x2_ = sX[(xrow + 2) * XS + (TIDX)]; \
    _Pragma("unroll") \
    for (int r_ = 0; r_ < 4; r_++){ \
      F0[r_] = fmaf(Wf[0][r_][2], x2_, fmaf(Wf[0][r_][1], x1_, fmaf(Wf[0][r_][0], x0_, biasv[0][r_]))); \
      F1[r_] = fmaf(Wf[1][r_][2], x2_, fmaf(Wf[1][r_][1], x1_, fmaf(Wf[1][r_][0], x0_, biasv[1][r_]))); \
    } \
  } while(0)

  f32x4 FBa0, FBa1, FBb0, FBb1;
  {
    const int t0_ = dir ? (TT - 1) : 0;
    FFCOMP(FBa0, FBa1, t0_);
  }

#define L0STEP(S, P, FC0, FC1, FN0, FN1) do { \
    const int p1_ = (P) ^ 1; \
    short8 bh0 = *(const short8*)&sZ[P][m8][     quad * 8]; \
    short8 bh1 = *(const short8*)&sZ[P][m8][32 + quad * 8]; \
    if (lane < 8 && (S) > 0){ \
      const int tprev = dir ? (TT - (S)) : ((S) - 1); \
      uint4 v_ = *(const uint4*)&sZ[P][wv][lane * 8]; \
      *(uint4*)(y0 + ((size_t)(bbase + wv) * TT + tprev) * 128 + dir * 64 + lane * 8) = v_; \
    } \
    f32x4 A0 = MF(aH[0][0], bh0, FC0); \
    f32x4 A1 = MF(aH[1][0], bh0, FC1); \
    A0 = MF(aH[0][1], bh1, A0); \
    A1 = MF(aH[1][1], bh1, A1); \
    { int sn_ = (S) + 1; if (sn_ > TT - 1) sn_ = TT - 1; \
      const int tn_ = dir ? (TT - 1 - sn_) : sn_; \
      FFCOMP(FN0, FN1, tn_); \
    } \
    __builtin_amdgcn_sched_barrier(0); \
    NONLIN_WRITE(A0, A1, p1_); \
    __builtin_amdgcn_sched_barrier(0); \
    lds_barrier(); \
  } while(0)

  for (int s = 0; s < TT; s += 4){
    L0STEP(s,     0, FBa0, FBa1, FBb0, FBb1);
    L0STEP(s + 1, 1, FBb0, FBb1, FBa0, FBa1);
    L0STEP(s + 2, 0, FBa0, FBa1, FBb0, FBb1);
    L0STEP(s + 3, 1, FBb0, FBb1, FBa0, FBa1);
  }
#undef L0STEP
#undef FFCOMP

  // final timestep's h (last write went to sZ[0])
  if (lane < 8){
    const int tl = dir ? 0 : (TT - 1);
    uint4 v = *(const uint4*)&sZ[0][wv][lane * 8];
    *(uint4*)(y0 + ((size_t)(bbase + wv) * TT + tl) * 128 + dir * 64 + lane * 8) = v;
  }
}

// ==================== Layer 1 ====================
// Issue-order pipeline, unroll-4 (compile-time ring slots); y0 via 4-slot LDS
// ring with distributed staging (wave w stages batch row w, lanes 0-15).
__global__ __launch_bounds__(512, 2) void lstm_l1(
    const unsigned short* __restrict__ y0,  // [B][T][128] bf16
    const float* __restrict__ Wih_f, const float* __restrict__ Whh_f,
    const float* __restrict__ bih_f, const float* __restrict__ bhh_f,
    const float* __restrict__ Wih_b, const float* __restrict__ Whh_b,
    const float* __restrict__ bih_b, const float* __restrict__ bhh_b,
    float* __restrict__ hT)                 // [B][128] fp32
{
  const int tid = threadIdx.x;
  const int wv = tid >> 6, lane = tid & 63;
  const int quad = lane >> 4, m16 = lane & 15;
  const int dir = blockIdx.y;
  const int bbase = blockIdx.x * 8;
  const float* Wih = dir ? Wih_b : Wih_f;
  const float* Whh = dir ? Whh_b : Whh_f;
  const float* bih = dir ? bih_b : bih_f;
  const float* bhh = dir ? bhh_b : bhh_f;

  __shared__ __align__(16) unsigned short sZ[2][8][LSTR];
  __shared__ __align__(16) unsigned short sY[4][8][LSTR];   // 4-slot y0 ring

  short8 aY[2][4], aH[2][2];
  f32x4 biasv[2];
  const int gm = (m16 & 3) * 64 + (m16 >> 2);
  #pragma unroll
  for (int i = 0; i < 2; i++){
    const int rt = 2 * wv + i;
    const int g = gm + 4 * rt;
    #pragma unroll
    for (int kt = 0; kt < 4; kt++) aY[i][kt] = w8f32(Wih + g * 128 + kt * 32 + quad * 8);
    aH[i][0] = w8f32(Whh + g * 64 + quad * 8);
    aH[i][1] = w8f32(Whh + g * 64 + 32 + quad * 8);
    const int gu = 4 * rt + quad;
    #pragma unroll
    for (int r = 0; r < 4; r++) biasv[i][r] = bih[r * 64 + gu] + bhh[r * 64 + gu];
  }

  for (int idx = tid; idx < 2 * 8 * LSTR; idx += 512)
    ((unsigned short*)sZ)[idx] = 0;

  // distributed staging: wave w stages batch row w, lanes 0-15 (16B chunks)
  const bool stager = (lane < 16);
  const size_t sgbase = (size_t)(bbase + wv) * TT * 128 + (size_t)lane * 8;
  float4 hA = make_float4(0.f,0.f,0.f,0.f), hB = make_float4(0.f,0.f,0.f,0.f);
  if (stager){
    const int t0 = dir ? (TT-1) : 0, t1 = dir ? (TT-2) : 1, t2 = dir ? (TT-3) : 2;
    const int t3 = dir ? (TT-4) : 3, t4 = dir ? (TT-5) : 4;
    float4 v0 = *(const float4*)(y0 + sgbase + (size_t)t0 * 128);
    float4 v1 = *(const float4*)(y0 + sgbase + (size_t)t1 * 128);
    float4 v2 = *(const float4*)(y0 + sgbase + (size_t)t2 * 128);
    hA = *(const float4*)(y0 + sgbase + (size_t)t3 * 128);
    hB = *(const float4*)(y0 + sgbase + (size_t)t4 * 128);
    *(float4*)&sY[0][wv][lane * 8] = v0;
    *(float4*)&sY[1][wv][lane * 8] = v1;
    *(float4*)&sY[2][wv][lane * 8] = v2;
  }
  __syncthreads();

  const int m8 = m16 & 7;
  const bool sel0 = (m16 < 8);
  const int colw = 8 * wv + quad + ((m16 >> 3) << 2);
  float c = 0.f, h = 0.f;

  // FF(0) from ring slot 0
  f32x4 FBa0, FBa1, FBb0, FBb1;
  {
    short8 by0 = *(const short8*)&sY[0][m8][     quad * 8];
    short8 by1 = *(const short8*)&sY[0][m8][32 + quad * 8];
    short8 by2 = *(const short8*)&sY[0][m8][64 + quad * 8];
    short8 by3 = *(const short8*)&sY[0][m8][96 + quad * 8];
    FBa0 = MF(aY[0][0], by0, biasv[0]);
    FBa1 = MF(aY[1][0], by0, biasv[1]);
    FBa0 = MF(aY[0][1], by1, FBa0);  FBa1 = MF(aY[1][1], by1, FBa1);
    FBa0 = MF(aY[0][2], by2, FBa0);  FBa1 = MF(aY[1][2], by2, FBa1);
    FBa0 = MF(aY[0][3], by3, FBa0);  FBa1 = MF(aY[1][3], by3, FBa1);
  }

#define L1STEP(S, P, SLOT, WSLOT, HOLD, FC0, FC1, FN0, FN1) do { \
    const int p1_ = (P) ^ 1; \
    short8 bh0 = *(const short8*)&sZ[P][m8][     quad * 8]; \
    short8 bh1 = *(const short8*)&sZ[P][m8][32 + quad * 8]; \
    short8 by0 = *(const short8*)&sY[SLOT][m8][     quad * 8]; \
    short8 by1 = *(const short8*)&sY[SLOT][m8][32 + quad * 8]; \
    short8 by2 = *(const short8*)&sY[SLOT][m8][64 + quad * 8]; \
    short8 by3 = *(const short8*)&sY[SLOT][m8][96 + quad * 8]; \
    f32x4 A0 = MF(aH[0][0], bh0, FC0); \
    f32x4 A1 = MF(aH[1][0], bh0, FC1); \
    A0 = MF(aH[0][1], bh1, A0); \
    A1 = MF(aH[1][1], bh1, A1); \
    FN0 = MF(aY[0][0], by0, biasv[0]); \
    FN1 = MF(aY[1][0], by0, biasv[1]); \
    FN0 = MF(aY[0][1], by1, FN0);  FN1 = MF(aY[1][1], by1, FN1); \
    FN0 = MF(aY[0][2], by2, FN0);  FN1 = MF(aY[1][2], by2, FN1); \
    FN0 = MF(aY[0][3], by3, FN0);  FN1 = MF(aY[1][3], by3, FN1); \
    __builtin_amdgcn_sched_barrier(0); \
    NONLIN_WRITE(A0, A1, p1_); \
    if ((S) == TT - 1){ \
      hT[(size_t)(bbase + m8) * 128 + dir * 64 + colw] = h; \
    } \
    if (stager){ \
      *(float4*)&sY[WSLOT][wv][lane * 8] = HOLD; \
      int sg_ = (S) + 5; if (sg_ > TT - 1) sg_ = TT - 1; \
      const int tg_ = dir ? (TT - 1 - sg_) : sg_; \
      HOLD = *(const float4*)(y0 + sgbase + (size_t)tg_ * 128); \
    } \
    __builtin_amdgcn_sched_barrier(0); \
    lds_barrier(); \
  } while(0)

  for (int s = 0; s < TT; s += 4){
    L1STEP(s,     0, 1, 3, hA, FBa0, FBa1, FBb0, FBb1);
    L1STEP(s + 1, 1, 2, 0, hB, FBb0, FBb1, FBa0, FBa1);
    L1STEP(s + 2, 0, 3, 1, hA, FBa0, FBa1, FBb0, FBb1);
    L1STEP(s + 3, 1, 0, 2, hB, FBb0, FBb1, FBa0, FBa1);
  }
#undef L1STEP
}

// ==================== FC head ====================
__global__ __launch_bounds__(256, 1) void fc_kernel(
    const float* __restrict__ hT,
    const float* __restrict__ w1, const float* __restrict__ b1,
    const float* __restrict__ w2, const float* __restrict__ b2,
    float* __restrict__ out)
{
  __shared__ float sh[4][64];
  const int wave = threadIdx.x >> 6, lane = threadIdx.x & 63;
  const int b = blockIdx.x * 4 + wave;
  float acc = b1[lane];
  const float* hrow = hT + (size_t)b * 128;
  #pragma unroll
  for (int k = 0; k < 128; k += 4){
    float4 h4 = *(const float4*)(hrow + k);
    float4 w4 = *(const float4*)(w1 + lane * 128 + k);
    acc = fmaf(w4.x, h4.x, acc);
    acc = fmaf(w4.y, h4.y, acc);
    acc = fmaf(w4.z, h4.z, acc);
    acc = fmaf(w4.w, h4.w, acc);
  }
  sh[wave][lane] = fmaxf(acc, 0.f);
  __syncthreads();
  if (lane < 2){
    float a = b2[lane];
    #pragma unroll
    for (int k = 0; k < 64; k++) a = fmaf(w2[lane * 64 + k], sh[wave][k], a);
    out[(size_t)b * 2 + lane] = a;
  }
}

extern "C" void kernel_launch(void* const* d_in, const int* in_sizes, int n_in,
                              void* d_out, int out_size, void* d_ws, size_t ws_size,
                              hipStream_t stream){
  (void)in_sizes; (void)n_in; (void)out_size; (void)ws_size;
  const float* x     = (const float*)d_in[0];
  const float* Wih0f = (const float*)d_in[1];
  const float* Whh0f = (const float*)d_in[2];
  const float* bih0f = (const float*)d_in[3];
  const float* bhh0f = (const float*)d_in[4];
  const float* Wih0b = (const float*)d_in[5];
  const float* Whh0b = (const float*)d_in[6];
  const float* bih0b = (const float*)d_in[7];
  const float* bhh0b = (const float*)d_in[8];
  const float* Wih1f = (const float*)d_in[9];
  const float* Whh1f = (const float*)d_in[10];
  const float* bih1f = (const float*)d_in[11];
  const float* bhh1f = (const float*)d_in[12];
  const float* Wih1b = (const float*)d_in[13];
  const float* Whh1b = (const float*)d_in[14];
  const float* bih1b = (const float*)d_in[15];
  const float* bhh1b = (const float*)d_in[16];
  const float* fc1W  = (const float*)d_in[17];
  const float* fc1b  = (const float*)d_in[18];
  const float* fc2W  = (const float*)d_in[19];
  const float* fc2b  = (const float*)d_in[20];
  float* out = (float*)d_out;

  unsigned short* y0 = (unsigned short*)d_ws;                       // 134,217,728 B
  float* hT = (float*)((char*)d_ws + (size_t)1024 * TT * 128 * 2);

  dim3 grid(128, 2), block(512);
  lstm_l0<<<grid, block, 0, stream>>>(x, Wih0f, Whh0f, bih0f, bhh0f,
                                      Wih0b, Whh0b, bih0b, bhh0b, y0);
  lstm_l1<<<grid, block, 0, stream>>>(y0, Wih1f, Whh1f, bih1f, bhh1f,
                                      Wih1b, Whh1b, bih1b, bhh1b, hT);
  fc_kernel<<<dim3(256), dim3(256), 0, stream>>>(hT, fc1W, fc1b, fc2W, fc2b, out);
}

// Round 10
// 517.140 us; speedup vs baseline: 1.6336x; 1.0260x over previous
//
#include <hip/hip_runtime.h>
#include <stdint.h>

typedef __attribute__((ext_vector_type(8))) short short8;
typedef __attribute__((ext_vector_type(4))) float f32x4;

#define TT 512
#define LSTR 136   // sZ/sY row stride in ushorts: 272B -> spread banks
#define XS 516     // sX row stride in floats

static __device__ __forceinline__ uint32_t f2bf_u(float f){
  union { float f; uint32_t u; } v; v.f = f;
  return (v.u + 0x7fffu + ((v.u >> 16) & 1u)) >> 16;
}
static __device__ __forceinline__ short8 w8f32(const float* p){
  float4 a = *(const float4*)p;
  float4 b = *(const float4*)(p + 4);
  short8 r;
  r[0] = (short)f2bf_u(a.x); r[1] = (short)f2bf_u(a.y);
  r[2] = (short)f2bf_u(a.z); r[3] = (short)f2bf_u(a.w);
  r[4] = (short)f2bf_u(b.x); r[5] = (short)f2bf_u(b.y);
  r[6] = (short)f2bf_u(b.z); r[7] = (short)f2bf_u(b.w);
  return r;
}
// sigmoid via exp2+rcp: inf-safe (exp2->inf => rcp->0).
static __device__ __forceinline__ float sigx(float x){
  float e = __builtin_amdgcn_exp2f(-1.442695040888963f * x);
  return __builtin_amdgcn_rcpf(1.f + e);
}
// tanh(x) = 2*sigmoid(2x)-1: no clamp needed.
static __device__ __forceinline__ float tanhx(float x){
  float e = __builtin_amdgcn_exp2f(-2.885390081777927f * x);
  return fmaf(__builtin_amdgcn_rcpf(1.f + e), 2.f, -1.f);
}
// LDS-only barrier: waits ds ops, leaves global loads/stores in flight.
static __device__ __forceinline__ void lds_barrier(){
  asm volatile("s_waitcnt lgkmcnt(0)" ::: "memory");
  __builtin_amdgcn_s_barrier();
}
#define MF(A,B,C) __builtin_amdgcn_mfma_f32_16x16x32_bf16((A),(B),(C),0,0,0)

// ==================== Layer 0 ====================
// 256 thr / 4 waves / 4 batches per block; grid (256,2) -> 2 blocks/CU for
// barrier-stall overlap. Wave w owns 16 units via 4 MFMA chains (C = 0-init);
// lane selects its chain (copy = m16>>2) via cndmask, adds its OWN per-unit
// FF (bias + Wih*x, 12 fmaf), then nonlin. sZ has 4 batch rows; B-operand
// cols 4-15 broadcast-read row m16&3.
__global__ __launch_bounds__(256, 2) void lstm_l0(
    const float* __restrict__ x,   // [B][3][T]
    const float* __restrict__ Wih_f, const float* __restrict__ Whh_f,
    const float* __restrict__ bih_f, const float* __restrict__ bhh_f,
    const float* __restrict__ Wih_b, const float* __restrict__ Whh_b,
    const float* __restrict__ bih_b, const float* __restrict__ bhh_b,
    unsigned short* __restrict__ y0)  // [B][T][128] bf16
{
  const int tid = threadIdx.x;
  const int wv = tid >> 6, lane = tid & 63;
  const int quad = lane >> 4, m16 = lane & 15;
  const int dir = blockIdx.y;
  const int bbase = blockIdx.x * 4;
  const float* Wih = dir ? Wih_b : Wih_f;
  const float* Whh = dir ? Whh_b : Whh_f;
  const float* bih = dir ? bih_b : bih_f;
  const float* bhh = dir ? bhh_b : bhh_f;

  __shared__ __align__(16) unsigned short sZ[2][4][LSTR];
  __shared__ __align__(16) float sX[12 * XS];

  const int copy = m16 >> 2;            // chain select 0..3
  const int batch = m16 & 3;
  const int unit = 16 * wv + 4 * copy + quad;
  const bool selA = (copy & 1) != 0;
  const bool selB = (copy & 2) != 0;

  // A-frags: chain k covers units 16wv+4k..+3 (gate-major rows).
  short8 aH[4][2];
  const int gm = (m16 & 3) * 64 + (m16 >> 2);
  #pragma unroll
  for (int k = 0; k < 4; k++){
    const int g = gm + 4 * (4 * wv + k);
    aH[k][0] = w8f32(Whh + g * 64 + quad * 8);
    aH[k][1] = w8f32(Whh + g * 64 + 32 + quad * 8);
  }
  // own-unit FF weights + bias
  float Wf[4][3];
  f32x4 biasF;
  #pragma unroll
  for (int r = 0; r < 4; r++){
    biasF[r] = bih[r * 64 + unit] + bhh[r * 64 + unit];
    #pragma unroll
    for (int d = 0; d < 3; d++) Wf[r][d] = Wih[(r * 64 + unit) * 3 + d];
  }

  for (int idx = tid; idx < 2 * 4 * LSTR; idx += 256)
    ((unsigned short*)sZ)[idx] = 0;
  for (int i4 = tid; i4 < 1536; i4 += 256){
    const int row = i4 >> 7, t4 = (i4 & 127) * 4;
    *(float4*)&sX[row * XS + t4] = *(const float4*)(x + (size_t)bbase * 1536 + row * 512 + t4);
  }
  __syncthreads();

  const int xrow = 3 * batch;
  float c = 0.f, h = 0.f;
  const f32x4 z4 = {0.f, 0.f, 0.f, 0.f};

  // FF(t) for own unit: F[r] = bias + Wih*x(t)
#define FFCOMP(F, TIDX) do { \
    float x0_ = sX[xrow * XS + (TIDX)]; \
    float x1_ = sX[(xrow + 1) * XS + (TIDX)]; \
    float x2_ = sX[(xrow + 2) * XS + (TIDX)]; \
    _Pragma("unroll") \
    for (int r_ = 0; r_ < 4; r_++) \
      F[r_] = fmaf(Wf[r_][2], x2_, fmaf(Wf[r_][1], x1_, fmaf(Wf[r_][0], x0_, biasF[r_]))); \
  } while(0)

  f32x4 FBa, FBb;
  {
    const int t0_ = dir ? (TT - 1) : 0;
    FFCOMP(FBa, t0_);
  }

#define L0STEP(S, P, FC, FN) do { \
    const int p1_ = (P) ^ 1; \
    short8 bh0 = *(const short8*)&sZ[P][batch][     quad * 8]; \
    short8 bh1 = *(const short8*)&sZ[P][batch][32 + quad * 8]; \
    if (wv == 3 && lane < 32 && (S) > 0){ \
      const int tprev = dir ? (TT - (S)) : ((S) - 1); \
      const int br_ = lane >> 3, cc_ = lane & 7; \
      uint4 v_ = *(const uint4*)&sZ[P][br_][cc_ * 8]; \
      *(uint4*)(y0 + ((size_t)(bbase + br_) * TT + tprev) * 128 + dir * 64 + cc_ * 8) = v_; \
    } \
    f32x4 C0 = MF(aH[0][0], bh0, z4); \
    f32x4 C1 = MF(aH[1][0], bh0, z4); \
    f32x4 C2 = MF(aH[2][0], bh0, z4); \
    f32x4 C3 = MF(aH[3][0], bh0, z4); \
    C0 = MF(aH[0][1], bh1, C0); \
    C1 = MF(aH[1][1], bh1, C1); \
    C2 = MF(aH[2][1], bh1, C2); \
    C3 = MF(aH[3][1], bh1, C3); \
    { int sn_ = (S) + 1; if (sn_ > TT - 1) sn_ = TT - 1; \
      const int tn_ = dir ? (TT - 1 - sn_) : sn_; \
      FFCOMP(FN, tn_); \
    } \
    __builtin_amdgcn_sched_barrier(0); \
    { \
      float g0_ = (selB ? (selA ? C3[0] : C2[0]) : (selA ? C1[0] : C0[0])) + FC[0]; \
      float g1_ = (selB ? (selA ? C3[1] : C2[1]) : (selA ? C1[1] : C0[1])) + FC[1]; \
      float g2_ = (selB ? (selA ? C3[2] : C2[2]) : (selA ? C1[2] : C0[2])) + FC[2]; \
      float g3_ = (selB ? (selA ? C3[3] : C2[3]) : (selA ? C1[3] : C0[3])) + FC[3]; \
      float ii_ = sigx(g0_), ff_ = sigx(g1_), gg_ = tanhx(g2_), oo_ = sigx(g3_); \
      c = fmaf(ff_, c, ii_ * gg_); \
      h = oo_ * tanhx(c); \
      sZ[p1_][batch][unit] = (unsigned short)f2bf_u(h); \
    } \
    __builtin_amdgcn_sched_barrier(0); \
    lds_barrier(); \
  } while(0)

  for (int s = 0; s < TT; s += 2){
    L0STEP(s,     0, FBa, FBb);
    L0STEP(s + 1, 1, FBb, FBa);
  }
#undef L0STEP
#undef FFCOMP

  // final timestep's h (last write went to sZ[0])
  if (wv == 3 && lane < 32){
    const int tl = dir ? 0 : (TT - 1);
    const int br = lane >> 3, cc = lane & 7;
    uint4 v = *(const uint4*)&sZ[0][br][cc * 8];
    *(uint4*)(y0 + ((size_t)(bbase + br) * TT + tl) * 128 + dir * 64 + cc * 8) = v;
  }
}

// ==================== Layer 1 ====================
// Unchanged from round 9: issue-order pipeline, unroll-4 ring slots,
// distributed staging, 8-row sZ, redistributed nonlin.
#define NONLIN_WRITE(A0V, A1V, P1) do { \
    float g0_ = sel0 ? (A0V)[0] : (A1V)[0]; \
    float g1_ = sel0 ? (A0V)[1] : (A1V)[1]; \
    float g2_ = sel0 ? (A0V)[2] : (A1V)[2]; \
    float g3_ = sel0 ? (A0V)[3] : (A1V)[3]; \
    float ii_ = sigx(g0_), ff_ = sigx(g1_), gg_ = tanhx(g2_), oo_ = sigx(g3_); \
    c = fmaf(ff_, c, ii_ * gg_); \
    h = oo_ * tanhx(c); \
    sZ[P1][m8][colw] = (unsigned short)f2bf_u(h); \
  } while(0)

__global__ __launch_bounds__(512, 2) void lstm_l1(
    const unsigned short* __restrict__ y0,  // [B][T][128] bf16
    const float* __restrict__ Wih_f, const float* __restrict__ Whh_f,
    const float* __restrict__ bih_f, const float* __restrict__ bhh_f,
    const float* __restrict__ Wih_b, const float* __restrict__ Whh_b,
    const float* __restrict__ bih_b, const float* __restrict__ bhh_b,
    float* __restrict__ hT)                 // [B][128] fp32
{
  const int tid = threadIdx.x;
  const int wv = tid >> 6, lane = tid & 63;
  const int quad = lane >> 4, m16 = lane & 15;
  const int dir = blockIdx.y;
  const int bbase = blockIdx.x * 8;
  const float* Wih = dir ? Wih_b : Wih_f;
  const float* Whh = dir ? Whh_b : Whh_f;
  const float* bih = dir ? bih_b : bih_f;
  const float* bhh = dir ? bhh_b : bhh_f;

  __shared__ __align__(16) unsigned short sZ[2][8][LSTR];
  __shared__ __align__(16) unsigned short sY[4][8][LSTR];   // 4-slot y0 ring

  short8 aY[2][4], aH[2][2];
  f32x4 biasv[2];
  const int gm = (m16 & 3) * 64 + (m16 >> 2);
  #pragma unroll
  for (int i = 0; i < 2; i++){
    const int rt = 2 * wv + i;
    const int g = gm + 4 * rt;
    #pragma unroll
    for (int kt = 0; kt < 4; kt++) aY[i][kt] = w8f32(Wih + g * 128 + kt * 32 + quad * 8);
    aH[i][0] = w8f32(Whh + g * 64 + quad * 8);
    aH[i][1] = w8f32(Whh + g * 64 + 32 + quad * 8);
    const int gu = 4 * rt + quad;
    #pragma unroll
    for (int r = 0; r < 4; r++) biasv[i][r] = bih[r * 64 + gu] + bhh[r * 64 + gu];
  }

  for (int idx = tid; idx < 2 * 8 * LSTR; idx += 512)
    ((unsigned short*)sZ)[idx] = 0;

  // distributed staging: wave w stages batch row w, lanes 0-15 (16B chunks)
  const bool stager = (lane < 16);
  const size_t sgbase = (size_t)(bbase + wv) * TT * 128 + (size_t)lane * 8;
  float4 hA = make_float4(0.f,0.f,0.f,0.f), hB = make_float4(0.f,0.f,0.f,0.f);
  if (stager){
    const int t0 = dir ? (TT-1) : 0, t1 = dir ? (TT-2) : 1, t2 = dir ? (TT-3) : 2;
    const int t3 = dir ? (TT-4) : 3, t4 = dir ? (TT-5) : 4;
    float4 v0 = *(const float4*)(y0 + sgbase + (size_t)t0 * 128);
    float4 v1 = *(const float4*)(y0 + sgbase + (size_t)t1 * 128);
    float4 v2 = *(const float4*)(y0 + sgbase + (size_t)t2 * 128);
    hA = *(const float4*)(y0 + sgbase + (size_t)t3 * 128);
    hB = *(const float4*)(y0 + sgbase + (size_t)t4 * 128);
    *(float4*)&sY[0][wv][lane * 8] = v0;
    *(float4*)&sY[1][wv][lane * 8] = v1;
    *(float4*)&sY[2][wv][lane * 8] = v2;
  }
  __syncthreads();

  const int m8 = m16 & 7;
  const bool sel0 = (m16 < 8);
  const int colw = 8 * wv + quad + ((m16 >> 3) << 2);
  float c = 0.f, h = 0.f;

  // FF(0) from ring slot 0
  f32x4 FBa0, FBa1, FBb0, FBb1;
  {
    short8 by0 = *(const short8*)&sY[0][m8][     quad * 8];
    short8 by1 = *(const short8*)&sY[0][m8][32 + quad * 8];
    short8 by2 = *(const short8*)&sY[0][m8][64 + quad * 8];
    short8 by3 = *(const short8*)&sY[0][m8][96 + quad * 8];
    FBa0 = MF(aY[0][0], by0, biasv[0]);
    FBa1 = MF(aY[1][0], by0, biasv[1]);
    FBa0 = MF(aY[0][1], by1, FBa0);  FBa1 = MF(aY[1][1], by1, FBa1);
    FBa0 = MF(aY[0][2], by2, FBa0);  FBa1 = MF(aY[1][2], by2, FBa1);
    FBa0 = MF(aY[0][3], by3, FBa0);  FBa1 = MF(aY[1][3], by3, FBa1);
  }

#define L1STEP(S, P, SLOT, WSLOT, HOLD, FC0, FC1, FN0, FN1) do { \
    const int p1_ = (P) ^ 1; \
    short8 bh0 = *(const short8*)&sZ[P][m8][     quad * 8]; \
    short8 bh1 = *(const short8*)&sZ[P][m8][32 + quad * 8]; \
    short8 by0 = *(const short8*)&sY[SLOT][m8][     quad * 8]; \
    short8 by1 = *(const short8*)&sY[SLOT][m8][32 + quad * 8]; \
    short8 by2 = *(const short8*)&sY[SLOT][m8][64 + quad * 8]; \
    short8 by3 = *(const short8*)&sY[SLOT][m8][96 + quad * 8]; \
    f32x4 A0 = MF(aH[0][0], bh0, FC0); \
    f32x4 A1 = MF(aH[1][0], bh0, FC1); \
    A0 = MF(aH[0][1], bh1, A0); \
    A1 = MF(aH[1][1], bh1, A1); \
    FN0 = MF(aY[0][0], by0, biasv[0]); \
    FN1 = MF(aY[1][0], by0, biasv[1]); \
    FN0 = MF(aY[0][1], by1, FN0);  FN1 = MF(aY[1][1], by1, FN1); \
    FN0 = MF(aY[0][2], by2, FN0);  FN1 = MF(aY[1][2], by2, FN1); \
    FN0 = MF(aY[0][3], by3, FN0);  FN1 = MF(aY[1][3], by3, FN1); \
    __builtin_amdgcn_sched_barrier(0); \
    NONLIN_WRITE(A0, A1, p1_); \
    if ((S) == TT - 1){ \
      hT[(size_t)(bbase + m8) * 128 + dir * 64 + colw] = h; \
    } \
    if (stager){ \
      *(float4*)&sY[WSLOT][wv][lane * 8] = HOLD; \
      int sg_ = (S) + 5; if (sg_ > TT - 1) sg_ = TT - 1; \
      const int tg_ = dir ? (TT - 1 - sg_) : sg_; \
      HOLD = *(const float4*)(y0 + sgbase + (size_t)tg_ * 128); \
    } \
    __builtin_amdgcn_sched_barrier(0); \
    lds_barrier(); \
  } while(0)

  for (int s = 0; s < TT; s += 4){
    L1STEP(s,     0, 1, 3, hA, FBa0, FBa1, FBb0, FBb1);
    L1STEP(s + 1, 1, 2, 0, hB, FBb0, FBb1, FBa0, FBa1);
    L1STEP(s + 2, 0, 3, 1, hA, FBa0, FBa1, FBb0, FBb1);
    L1STEP(s + 3, 1, 0, 2, hB, FBb0, FBb1, FBa0, FBa1);
  }
#undef L1STEP
}

// ==================== FC head ====================
__global__ __launch_bounds__(256, 1) void fc_kernel(
    const float* __restrict__ hT,
    const float* __restrict__ w1, const float* __restrict__ b1,
    const float* __restrict__ w2, const float* __restrict__ b2,
    float* __restrict__ out)
{
  __shared__ float sh[4][64];
  const int wave = threadIdx.x >> 6, lane = threadIdx.x & 63;
  const int b = blockIdx.x * 4 + wave;
  float acc = b1[lane];
  const float* hrow = hT + (size_t)b * 128;
  #pragma unroll
  for (int k = 0; k < 128; k += 4){
    float4 h4 = *(const float4*)(hrow + k);
    float4 w4 = *(const float4*)(w1 + lane * 128 + k);
    acc = fmaf(w4.x, h4.x, acc);
    acc = fmaf(w4.y, h4.y, acc);
    acc = fmaf(w4.z, h4.z, acc);
    acc = fmaf(w4.w, h4.w, acc);
  }
  sh[wave][lane] = fmaxf(acc, 0.f);
  __syncthreads();
  if (lane < 2){
    float a = b2[lane];
    #pragma unroll
    for (int k = 0; k < 64; k++) a = fmaf(w2[lane * 64 + k], sh[wave][k], a);
    out[(size_t)b * 2 + lane] = a;
  }
}

extern "C" void kernel_launch(void* const* d_in, const int* in_sizes, int n_in,
                              void* d_out, int out_size, void* d_ws, size_t ws_size,
                              hipStream_t stream){
  (void)in_sizes; (void)n_in; (void)out_size; (void)ws_size;
  const float* x     = (const float*)d_in[0];
  const float* Wih0f = (const float*)d_in[1];
  const float* Whh0f = (const float*)d_in[2];
  const float* bih0f = (const float*)d_in[3];
  const float* bhh0f = (const float*)d_in[4];
  const float* Wih0b = (const float*)d_in[5];
  const float* Whh0b = (const float*)d_in[6];
  const float* bih0b = (const float*)d_in[7];
  const float* bhh0b = (const float*)d_in[8];
  const float* Wih1f = (const float*)d_in[9];
  const float* Whh1f = (const float*)d_in[10];
  const float* bih1f = (const float*)d_in[11];
  const float* bhh1f = (const float*)d_in[12];
  const float* Wih1b = (const float*)d_in[13];
  const float* Whh1b = (const float*)d_in[14];
  const float* bih1b = (const float*)d_in[15];
  const float* bhh1b = (const float*)d_in[16];
  const float* fc1W  = (const float*)d_in[17];
  const float* fc1b  = (const float*)d_in[18];
  const float* fc2W  = (const float*)d_in[19];
  const float* fc2b  = (const float*)d_in[20];
  float* out = (float*)d_out;

  unsigned short* y0 = (unsigned short*)d_ws;                       // 134,217,728 B
  float* hT = (float*)((char*)d_ws + (size_t)1024 * TT * 128 * 2);

  lstm_l0<<<dim3(256, 2), dim3(256), 0, stream>>>(x, Wih0f, Whh0f, bih0f, bhh0f,
                                                  Wih0b, Whh0b, bih0b, bhh0b, y0);
  lstm_l1<<<dim3(128, 2), dim3(512), 0, stream>>>(y0, Wih1f, Whh1f, bih1f, bhh1f,
                                                  Wih1b, Whh1b, bih1b, bhh1b, hT);
  fc_kernel<<<dim3(256), dim3(256), 0, stream>>>(hT, fc1W, fc1b, fc2W, fc2b, out);
}

// Round 11
// 513.298 us; speedup vs baseline: 1.6459x; 1.0075x over previous
//
#include <hip/hip_runtime.h>
#include <stdint.h>

typedef __attribute__((ext_vector_type(8))) short short8;
typedef __attribute__((ext_vector_type(4))) float f32x4;

#define TT 512
#define LSTR 136   // sZ/sY row stride in ushorts: 272B -> spread banks
#define XS 516     // sX row stride in floats

static __device__ __forceinline__ uint32_t f2bf_u(float f){
  union { float f; uint32_t u; } v; v.f = f;
  return (v.u + 0x7fffu + ((v.u >> 16) & 1u)) >> 16;
}
static __device__ __forceinline__ short8 w8f32(const float* p){
  float4 a = *(const float4*)p;
  float4 b = *(const float4*)(p + 4);
  short8 r;
  r[0] = (short)f2bf_u(a.x); r[1] = (short)f2bf_u(a.y);
  r[2] = (short)f2bf_u(a.z); r[3] = (short)f2bf_u(a.w);
  r[4] = (short)f2bf_u(b.x); r[5] = (short)f2bf_u(b.y);
  r[6] = (short)f2bf_u(b.z); r[7] = (short)f2bf_u(b.w);
  return r;
}
// sigmoid via exp2+rcp: inf-safe (exp2->inf => rcp->0).
static __device__ __forceinline__ float sigx(float x){
  float e = __builtin_amdgcn_exp2f(-1.442695040888963f * x);
  return __builtin_amdgcn_rcpf(1.f + e);
}
// tanh(x) = 2*sigmoid(2x)-1: no clamp needed.
static __device__ __forceinline__ float tanhx(float x){
  float e = __builtin_amdgcn_exp2f(-2.885390081777927f * x);
  return fmaf(__builtin_amdgcn_rcpf(1.f + e), 2.f, -1.f);
}
// LDS-only barrier: waits ds ops, leaves global loads/stores in flight.
static __device__ __forceinline__ void lds_barrier(){
  asm volatile("s_waitcnt lgkmcnt(0)" ::: "memory");
  __builtin_amdgcn_s_barrier();
}
#define MF(A,B,C) __builtin_amdgcn_mfma_f32_16x16x32_bf16((A),(B),(C),0,0,0)
// lane^8 exchange (convergent -> must be issued unconditionally)
#define SWZ(x) __int_as_float(__builtin_amdgcn_ds_swizzle(__float_as_int(x), 0x201F))

// ==================== Layer 0 ====================
// (unchanged from round 10) 256 thr / 4 waves / 4 batches; grid (256,2) ->
// 2 blocks/CU. 4 MFMA chains 0-init; own-unit VALU FF (12 fmaf); cndmask
// chain select; 4-row sZ with broadcast reads.
__global__ __launch_bounds__(256, 2) void lstm_l0(
    const float* __restrict__ x,   // [B][3][T]
    const float* __restrict__ Wih_f, const float* __restrict__ Whh_f,
    const float* __restrict__ bih_f, const float* __restrict__ bhh_f,
    const float* __restrict__ Wih_b, const float* __restrict__ Whh_b,
    const float* __restrict__ bih_b, const float* __restrict__ bhh_b,
    unsigned short* __restrict__ y0)  // [B][T][128] bf16
{
  const int tid = threadIdx.x;
  const int wv = tid >> 6, lane = tid & 63;
  const int quad = lane >> 4, m16 = lane & 15;
  const int dir = blockIdx.y;
  const int bbase = blockIdx.x * 4;
  const float* Wih = dir ? Wih_b : Wih_f;
  const float* Whh = dir ? Whh_b : Whh_f;
  const float* bih = dir ? bih_b : bih_f;
  const float* bhh = dir ? bhh_b : bhh_f;

  __shared__ __align__(16) unsigned short sZ[2][4][LSTR];
  __shared__ __align__(16) float sX[12 * XS];

  const int copy = m16 >> 2;
  const int batch = m16 & 3;
  const int unit = 16 * wv + 4 * copy + quad;
  const bool selA = (copy & 1) != 0;
  const bool selB = (copy & 2) != 0;

  short8 aH[4][2];
  const int gm = (m16 & 3) * 64 + (m16 >> 2);
  #pragma unroll
  for (int k = 0; k < 4; k++){
    const int g = gm + 4 * (4 * wv + k);
    aH[k][0] = w8f32(Whh + g * 64 + quad * 8);
    aH[k][1] = w8f32(Whh + g * 64 + 32 + quad * 8);
  }
  float Wf[4][3];
  f32x4 biasF;
  #pragma unroll
  for (int r = 0; r < 4; r++){
    biasF[r] = bih[r * 64 + unit] + bhh[r * 64 + unit];
    #pragma unroll
    for (int d = 0; d < 3; d++) Wf[r][d] = Wih[(r * 64 + unit) * 3 + d];
  }

  for (int idx = tid; idx < 2 * 4 * LSTR; idx += 256)
    ((unsigned short*)sZ)[idx] = 0;
  for (int i4 = tid; i4 < 1536; i4 += 256){
    const int row = i4 >> 7, t4 = (i4 & 127) * 4;
    *(float4*)&sX[row * XS + t4] = *(const float4*)(x + (size_t)bbase * 1536 + row * 512 + t4);
  }
  __syncthreads();

  const int xrow = 3 * batch;
  float c = 0.f, h = 0.f;
  const f32x4 z4 = {0.f, 0.f, 0.f, 0.f};

#define FFCOMP(F, TIDX) do { \
    float x0_ = sX[xrow * XS + (TIDX)]; \
    float x1_ = sX[(xrow + 1) * XS + (TIDX)]; \
    float x2_ = sX[(xrow + 2) * XS + (TIDX)]; \
    _Pragma("unroll") \
    for (int r_ = 0; r_ < 4; r_++) \
      F[r_] = fmaf(Wf[r_][2], x2_, fmaf(Wf[r_][1], x1_, fmaf(Wf[r_][0], x0_, biasF[r_]))); \
  } while(0)

  f32x4 FBa, FBb;
  {
    const int t0_ = dir ? (TT - 1) : 0;
    FFCOMP(FBa, t0_);
  }

#define L0STEP(S, P, FC, FN) do { \
    const int p1_ = (P) ^ 1; \
    short8 bh0 = *(const short8*)&sZ[P][batch][     quad * 8]; \
    short8 bh1 = *(const short8*)&sZ[P][batch][32 + quad * 8]; \
    if (wv == 3 && lane < 32 && (S) > 0){ \
      const int tprev = dir ? (TT - (S)) : ((S) - 1); \
      const int br_ = lane >> 3, cc_ = lane & 7; \
      uint4 v_ = *(const uint4*)&sZ[P][br_][cc_ * 8]; \
      *(uint4*)(y0 + ((size_t)(bbase + br_) * TT + tprev) * 128 + dir * 64 + cc_ * 8) = v_; \
    } \
    f32x4 C0 = MF(aH[0][0], bh0, z4); \
    f32x4 C1 = MF(aH[1][0], bh0, z4); \
    f32x4 C2 = MF(aH[2][0], bh0, z4); \
    f32x4 C3 = MF(aH[3][0], bh0, z4); \
    C0 = MF(aH[0][1], bh1, C0); \
    C1 = MF(aH[1][1], bh1, C1); \
    C2 = MF(aH[2][1], bh1, C2); \
    C3 = MF(aH[3][1], bh1, C3); \
    { int sn_ = (S) + 1; if (sn_ > TT - 1) sn_ = TT - 1; \
      const int tn_ = dir ? (TT - 1 - sn_) : sn_; \
      FFCOMP(FN, tn_); \
    } \
    __builtin_amdgcn_sched_barrier(0); \
    { \
      float g0_ = (selB ? (selA ? C3[0] : C2[0]) : (selA ? C1[0] : C0[0])) + FC[0]; \
      float g1_ = (selB ? (selA ? C3[1] : C2[1]) : (selA ? C1[1] : C0[1])) + FC[1]; \
      float g2_ = (selB ? (selA ? C3[2] : C2[2]) : (selA ? C1[2] : C0[2])) + FC[2]; \
      float g3_ = (selB ? (selA ? C3[3] : C2[3]) : (selA ? C1[3] : C0[3])) + FC[3]; \
      float ii_ = sigx(g0_), ff_ = sigx(g1_), gg_ = tanhx(g2_), oo_ = sigx(g3_); \
      c = fmaf(ff_, c, ii_ * gg_); \
      h = oo_ * tanhx(c); \
      sZ[p1_][batch][unit] = (unsigned short)f2bf_u(h); \
    } \
    __builtin_amdgcn_sched_barrier(0); \
    lds_barrier(); \
  } while(0)

  for (int s = 0; s < TT; s += 2){
    L0STEP(s,     0, FBa, FBb);
    L0STEP(s + 1, 1, FBb, FBa);
  }
#undef L0STEP
#undef FFCOMP

  if (wv == 3 && lane < 32){
    const int tl = dir ? 0 : (TT - 1);
    const int br = lane >> 3, cc = lane & 7;
    uint4 v = *(const uint4*)&sZ[0][br][cc * 8];
    *(uint4*)(y0 + ((size_t)(bbase + br) * TT + tl) * 128 + dir * 64 + cc * 8) = v;
  }
}

// ==================== Layer 1 ====================
// Dual-step FF: MFMA N-cols 0-7 = batches @ step s, 8-15 = batches @ s+1
// (per-lane slot select on sY read). One 8-MFMA FF set serves TWO steps ->
// 4 FF MFMA + 2 by-reads per step. Lane^8 ds_swizzle redistribution of the
// FF result happens one pair ahead, off the critical path. Rec MFMAs 0-init;
// gate base (bias+FF) added post-select.
__global__ __launch_bounds__(512, 2) void lstm_l1(
    const unsigned short* __restrict__ y0,  // [B][T][128] bf16
    const float* __restrict__ Wih_f, const float* __restrict__ Whh_f,
    const float* __restrict__ bih_f, const float* __restrict__ bhh_f,
    const float* __restrict__ Wih_b, const float* __restrict__ Whh_b,
    const float* __restrict__ bih_b, const float* __restrict__ bhh_b,
    float* __restrict__ hT)                 // [B][128] fp32
{
  const int tid = threadIdx.x;
  const int wv = tid >> 6, lane = tid & 63;
  const int quad = lane >> 4, m16 = lane & 15;
  const int dir = blockIdx.y;
  const int bbase = blockIdx.x * 8;
  const float* Wih = dir ? Wih_b : Wih_f;
  const float* Whh = dir ? Whh_b : Whh_f;
  const float* bih = dir ? bih_b : bih_f;
  const float* bhh = dir ? bhh_b : bhh_f;

  __shared__ __align__(16) unsigned short sZ[2][8][LSTR];
  __shared__ __align__(16) unsigned short sY[4][8][LSTR];   // 4-slot y0 ring

  short8 aY[2][4], aH[2][2];
  f32x4 biasv[2];
  const int gm = (m16 & 3) * 64 + (m16 >> 2);
  #pragma unroll
  for (int i = 0; i < 2; i++){
    const int rt = 2 * wv + i;
    const int g = gm + 4 * rt;
    #pragma unroll
    for (int kt = 0; kt < 4; kt++) aY[i][kt] = w8f32(Wih + g * 128 + kt * 32 + quad * 8);
    aH[i][0] = w8f32(Whh + g * 64 + quad * 8);
    aH[i][1] = w8f32(Whh + g * 64 + 32 + quad * 8);
    const int gu = 4 * rt + quad;
    #pragma unroll
    for (int r = 0; r < 4; r++) biasv[i][r] = bih[r * 64 + gu] + bhh[r * 64 + gu];
  }

  for (int idx = tid; idx < 2 * 8 * LSTR; idx += 512)
    ((unsigned short*)sZ)[idx] = 0;

  // prologue staging: slots 0..3 <- y(0..3); holds <- y(4), y(5)
  const bool stager = (lane < 16);
  const size_t sgbase = (size_t)(bbase + wv) * TT * 128 + (size_t)lane * 8;
  float4 hA = make_float4(0.f,0.f,0.f,0.f), hB = make_float4(0.f,0.f,0.f,0.f);
  if (stager){
    #pragma unroll
    for (int k = 0; k < 4; k++){
      const int tk = dir ? (TT - 1 - k) : k;
      *(float4*)&sY[k][wv][lane * 8] = *(const float4*)(y0 + sgbase + (size_t)tk * 128);
    }
    const int t4 = dir ? (TT - 5) : 4, t5 = dir ? (TT - 6) : 5;
    hA = *(const float4*)(y0 + sgbase + (size_t)t4 * 128);
    hB = *(const float4*)(y0 + sgbase + (size_t)t5 * 128);
  }
  __syncthreads();

  const int m8 = m16 & 7;
  const bool sel0 = (m16 < 8);
  const int colw = 8 * wv + quad + ((m16 >> 3) << 2);
  float c = 0.f, h = 0.f;
  const f32x4 z4 = {0.f, 0.f, 0.f, 0.f};

  const int SLOTU = 8 * LSTR;
  // per-lane y base: batch row m8, k-offset quad*8; lanes m16>=8 shift +1 slot
  const unsigned short* yb = &sY[0][0][0] + (sel0 ? 0 : SLOTU) + m8 * LSTR + quad * 8;

  // 8 FF MFMAs for pair at slot base SL (cols 0-7 step s, 8-15 step s+1)
#define FFMM(SL, FB0, FB1) do { \
    short8 by0 = *(const short8*)(yb + (SL) * SLOTU); \
    short8 by1 = *(const short8*)(yb + (SL) * SLOTU + 32); \
    short8 by2 = *(const short8*)(yb + (SL) * SLOTU + 64); \
    short8 by3 = *(const short8*)(yb + (SL) * SLOTU + 96); \
    FB0 = MF(aY[0][0], by0, biasv[0]); \
    FB1 = MF(aY[1][0], by0, biasv[1]); \
    FB0 = MF(aY[0][1], by1, FB0);  FB1 = MF(aY[1][1], by1, FB1); \
    FB0 = MF(aY[0][2], by2, FB0);  FB1 = MF(aY[1][2], by2, FB1); \
    FB0 = MF(aY[0][3], by3, FB0);  FB1 = MF(aY[1][3], by3, FB1); \
  } while(0)

  // redistribute FF pair: G0 (step s base), G1 (step s+1 base). All swizzles
  // unconditional (convergent op), selects on register values.
#define FFSWZ(FB0, FB1, G0, G1) do { \
    float w10_ = SWZ(FB1[0]), w11_ = SWZ(FB1[1]), w12_ = SWZ(FB1[2]), w13_ = SWZ(FB1[3]); \
    float w00_ = SWZ(FB0[0]), w01_ = SWZ(FB0[1]), w02_ = SWZ(FB0[2]), w03_ = SWZ(FB0[3]); \
    G0[0] = sel0 ? FB0[0] : w10_;  G0[1] = sel0 ? FB0[1] : w11_; \
    G0[2] = sel0 ? FB0[2] : w12_;  G0[3] = sel0 ? FB0[3] : w13_; \
    G1[0] = sel0 ? w00_ : FB1[0];  G1[1] = sel0 ? w01_ : FB1[1]; \
    G1[2] = sel0 ? w02_ : FB1[2];  G1[3] = sel0 ? w03_ : FB1[3]; \
  } while(0)

  f32x4 Ga0, Ga1, Gb0, Gb1, FBT0, FBT1;
  // FF(0),FF(1) from slots 0/1
  FFMM(0, FBT0, FBT1);
  FFSWZ(FBT0, FBT1, Ga0, Ga1);
  lds_barrier();   // protect slot 0/1 reads from step-0/1 stager overwrite

#define NONLIN1(R0, R1, GC, P1) do { \
    float g0_ = (sel0 ? (R0)[0] : (R1)[0]) + GC[0]; \
    float g1_ = (sel0 ? (R0)[1] : (R1)[1]) + GC[1]; \
    float g2_ = (sel0 ? (R0)[2] : (R1)[2]) + GC[2]; \
    float g3_ = (sel0 ? (R0)[3] : (R1)[3]) + GC[3]; \
    float ii_ = sigx(g0_), ff_ = sigx(g1_), gg_ = tanhx(g2_), oo_ = sigx(g3_); \
    c = fmaf(ff_, c, ii_ * gg_); \
    h = oo_ * tanhx(c); \
    sZ[P1][m8][colw] = (unsigned short)f2bf_u(h); \
  } while(0)

#define STAGE(S, WRSL, HOLD) do { \
    if (stager){ \
      *(float4*)&sY[WRSL][wv][lane * 8] = HOLD; \
      int sg_ = (S) + 6; if (sg_ > TT - 1) sg_ = TT - 1; \
      const int tg_ = dir ? (TT - 1 - sg_) : sg_; \
      HOLD = *(const float4*)(y0 + sgbase + (size_t)tg_ * 128); \
    } \
  } while(0)

  // even step: reads sZ[0], writes sZ[1]; issues next pair's FF MFMAs
#define L1STEPA(S, SLFF, WRSL, HOLD, GC) do { \
    short8 bh0 = *(const short8*)&sZ[0][m8][     quad * 8]; \
    short8 bh1 = *(const short8*)&sZ[0][m8][32 + quad * 8]; \
    f32x4 R0 = MF(aH[0][0], bh0, z4); \
    f32x4 R1 = MF(aH[1][0], bh0, z4); \
    R0 = MF(aH[0][1], bh1, R0); \
    R1 = MF(aH[1][1], bh1, R1); \
    FFMM(SLFF, FBT0, FBT1); \
    STAGE(S, WRSL, HOLD); \
    __builtin_amdgcn_sched_barrier(0); \
    NONLIN1(R0, R1, GC, 1); \
    __builtin_amdgcn_sched_barrier(0); \
    lds_barrier(); \
  } while(0)

  // odd step: reads sZ[1], writes sZ[0]; swizzles next pair's FF into GN
#define L1STEPB(S, WRSL, HOLD, GC, GN0, GN1) do { \
    short8 bh0 = *(const short8*)&sZ[1][m8][     quad * 8]; \
    short8 bh1 = *(const short8*)&sZ[1][m8][32 + quad * 8]; \
    f32x4 R0 = MF(aH[0][0], bh0, z4); \
    f32x4 R1 = MF(aH[1][0], bh0, z4); \
    R0 = MF(aH[0][1], bh1, R0); \
    R1 = MF(aH[1][1], bh1, R1); \
    FFSWZ(FBT0, FBT1, GN0, GN1); \
    STAGE(S, WRSL, HOLD); \
    __builtin_amdgcn_sched_barrier(0); \
    NONLIN1(R0, R1, GC, 0); \
    if ((S) == TT - 1){ \
      hT[(size_t)(bbase + m8) * 128 + dir * 64 + colw] = h; \
    } \
    __builtin_amdgcn_sched_barrier(0); \
    lds_barrier(); \
  } while(0)

  for (int s = 0; s < TT; s += 4){
    L1STEPA(s,     2, 0, hA, Ga0);            // FF for pair (s+2,s+3) from slots 2/3
    L1STEPB(s + 1,    1, hB, Ga1, Gb0, Gb1);
    L1STEPA(s + 2, 0, 2, hA, Gb0);            // FF for pair (s+4,s+5) from slots 0/1
    L1STEPB(s + 3,    3, hB, Gb1, Ga0, Ga1);
  }
#undef L1STEPA
#undef L1STEPB
#undef STAGE
#undef NONLIN1
#undef FFSWZ
#undef FFMM
}

// ==================== FC head ====================
__global__ __launch_bounds__(256, 1) void fc_kernel(
    const float* __restrict__ hT,
    const float* __restrict__ w1, const float* __restrict__ b1,
    const float* __restrict__ w2, const float* __restrict__ b2,
    float* __restrict__ out)
{
  __shared__ float sh[4][64];
  const int wave = threadIdx.x >> 6, lane = threadIdx.x & 63;
  const int b = blockIdx.x * 4 + wave;
  float acc = b1[lane];
  const float* hrow = hT + (size_t)b * 128;
  #pragma unroll
  for (int k = 0; k < 128; k += 4){
    float4 h4 = *(const float4*)(hrow + k);
    float4 w4 = *(const float4*)(w1 + lane * 128 + k);
    acc = fmaf(w4.x, h4.x, acc);
    acc = fmaf(w4.y, h4.y, acc);
    acc = fmaf(w4.z, h4.z, acc);
    acc = fmaf(w4.w, h4.w, acc);
  }
  sh[wave][lane] = fmaxf(acc, 0.f);
  __syncthreads();
  if (lane < 2){
    float a = b2[lane];
    #pragma unroll
    for (int k = 0; k < 64; k++) a = fmaf(w2[lane * 64 + k], sh[wave][k], a);
    out[(size_t)b * 2 + lane] = a;
  }
}

extern "C" void kernel_launch(void* const* d_in, const int* in_sizes, int n_in,
                              void* d_out, int out_size, void* d_ws, size_t ws_size,
                              hipStream_t stream){
  (void)in_sizes; (void)n_in; (void)out_size; (void)ws_size;
  const float* x     = (const float*)d_in[0];
  const float* Wih0f = (const float*)d_in[1];
  const float* Whh0f = (const float*)d_in[2];
  const float* bih0f = (const float*)d_in[3];
  const float* bhh0f = (const float*)d_in[4];
  const float* Wih0b = (const float*)d_in[5];
  const float* Whh0b = (const float*)d_in[6];
  const float* bih0b = (const float*)d_in[7];
  const float* bhh0b = (const float*)d_in[8];
  const float* Wih1f = (const float*)d_in[9];
  const float* Whh1f = (const float*)d_in[10];
  const float* bih1f = (const float*)d_in[11];
  const float* bhh1f = (const float*)d_in[12];
  const float* Wih1b = (const float*)d_in[13];
  const float* Whh1b = (const float*)d_in[14];
  const float* bih1b = (const float*)d_in[15];
  const float* bhh1b = (const float*)d_in[16];
  const float* fc1W  = (const float*)d_in[17];
  const float* fc1b  = (const float*)d_in[18];
  const float* fc2W  = (const float*)d_in[19];
  const float* fc2b  = (const float*)d_in[20];
  float* out = (float*)d_out;

  unsigned short* y0 = (unsigned short*)d_ws;                       // 134,217,728 B
  float* hT = (float*)((char*)d_ws + (size_t)1024 * TT * 128 * 2);

  lstm_l0<<<dim3(256, 2), dim3(256), 0, stream>>>(x, Wih0f, Whh0f, bih0f, bhh0f,
                                                  Wih0b, Whh0b, bih0b, bhh0b, y0);
  lstm_l1<<<dim3(128, 2), dim3(512), 0, stream>>>(y0, Wih1f, Whh1f, bih1f, bhh1f,
                                                  Wih1b, Whh1b, bih1b, bhh1b, hT);
  fc_kernel<<<dim3(256), dim3(256), 0, stream>>>(hT, fc1W, fc1b, fc2W, fc2b, out);
}